// Round 8
// baseline (262.293 us; speedup 1.0000x reference)
//
#include <hip/hip_runtime.h>
#include <cstddef>
#include <cstdint>

// ---------- types ----------
typedef __attribute__((ext_vector_type(8))) _Float16 half8;
typedef __attribute__((ext_vector_type(4))) _Float16 half4;
typedef __attribute__((ext_vector_type(4))) float f32x4;
typedef __attribute__((ext_vector_type(16))) float f32x16;

#define N_EMBD 1024
#define N_HEADS 16
#define BATCH 4
#define SEQ 2048
#define C3 3072
#define HD 64

template <int N> struct IC { static constexpr int value = N; };

__device__ inline uint32_t pk2(float x, float y) {
    auto h2 = __builtin_amdgcn_cvt_pkrtz(x, y);
    uint32_t u;
    __builtin_memcpy(&u, &h2, 4);
    return u;
}

__device__ inline void swap32(uint32_t& a, uint32_t& b) {
    asm volatile("v_permlane32_swap_b32 %0, %1" : "+v"(a), "+v"(b));
}

// ---------- fp32 -> fp16 convert ----------
__global__ void cvt_f32_f16(const float* __restrict__ in, _Float16* __restrict__ out, int n) {
    int i = (blockIdx.x * 256 + threadIdx.x) * 4;
    if (i >= n) return;
    float4 v = *(const float4*)(in + i);
    half4 h;
    h[0] = (_Float16)v.x; h[1] = (_Float16)v.y; h[2] = (_Float16)v.z; h[3] = (_Float16)v.w;
    *(half4*)(out + i) = h;
}

// ---------- transpose + convert: in[R][Ncols] f32 -> out[Ncols][R] f16 ----------
__global__ void transpose_cvt(const float* __restrict__ in, _Float16* __restrict__ out,
                              int R, int Ncols) {
    __shared__ float tile[32][33];
    int n0 = blockIdx.x * 32, r0 = blockIdx.y * 32;
    int tx = threadIdx.x, ty = threadIdx.y;  // 32 x 8
#pragma unroll
    for (int i = 0; i < 32; i += 8)
        tile[ty + i][tx] = in[(size_t)(r0 + ty + i) * Ncols + n0 + tx];
    __syncthreads();
#pragma unroll
    for (int i = 0; i < 32; i += 8)
        out[(size_t)(n0 + ty + i) * R + r0 + tx] = (_Float16)tile[tx][ty + i];
}

// ---------- V transpose: qkv V-part [T][64] -> vT[bh][64][T] (f16) ----------
__global__ void transpose_v(const _Float16* __restrict__ qkv, _Float16* __restrict__ vT) {
    __shared__ _Float16 tile[32][36];
    int t0 = blockIdx.x * 32;
    int bhd = blockIdx.y;           // bh*2 + dh
    int bh = bhd >> 1, dh = bhd & 1;
    int b = bh >> 4, h = bh & 15;
    int tx = threadIdx.x, ty = threadIdx.y;  // 32 x 8
#pragma unroll
    for (int i = 0; i < 32; i += 8)
        tile[ty + i][tx] = qkv[(size_t)(b * SEQ + t0 + ty + i) * C3 + 2 * N_EMBD + h * HD + dh * 32 + tx];
    __syncthreads();
#pragma unroll
    for (int i = 0; i < 32; i += 8)
        vT[((size_t)bh * HD + dh * 32 + ty + i) * SEQ + t0 + tx] = tile[tx][ty + i];
}

__device__ inline void store1(float* p, float v) { *p = v; }
__device__ inline void store1(_Float16* p, float v) { *p = (_Float16)v; }

// ---------- 256x192 4-phase GEMM (GEMM1): grid 512 = exactly 2 rounds ----------
template <typename OutT>
__global__ __launch_bounds__(512, 1) void gemm192(
    const _Float16* __restrict__ A, const _Float16* __restrict__ Bt,
    OutT* __restrict__ C, int M, int N, int K) {
    __shared__ _Float16 Al[2][256 * 64];
    __shared__ _Float16 Bl[2][192 * 64];
    const int tid = threadIdx.x;
    const int lane = tid & 63, wave = tid >> 6;
    const int l15 = lane & 15, l4 = lane >> 4;
    const int wm = wave >> 2, wn = wave & 3;

    const int nwg = gridDim.x, nbx = N / 192;
    int wg = blockIdx.x;
    if ((nwg & 7) == 0) { int cpx = nwg >> 3; wg = (wg & 7) * cpx + (wg >> 3); }
    const int row0 = (wg / nbx) * 256, col0 = (wg % nbx) * 192;
    const int TAU = K >> 6;

    const int srow = tid >> 3, su = tid & 7;
    const int usrc8 = (su ^ (srow & 7)) * 8;
    auto stageAu = [&](int unit, int ts) {
        __builtin_amdgcn_global_load_lds(
            (const __attribute__((address_space(1))) void*)(A + (size_t)(row0 + unit * 64 + srow) * K + ts * 64 + usrc8),
            (__attribute__((address_space(3))) void*)(&Al[ts & 1][unit * 64 * 64 + tid * 8]), 16, 0, 0);
    };
    auto stageBu = [&](int unit, int ts) {
        __builtin_amdgcn_global_load_lds(
            (const __attribute__((address_space(1))) void*)(Bt + (size_t)(col0 + unit * 64 + srow) * K + ts * 64 + usrc8),
            (__attribute__((address_space(3))) void*)(&Bl[ts & 1][unit * 64 * 64 + tid * 8]), 16, 0, 0);
    };
    auto stageTile = [&](int ts) {
        stageAu(0, ts); stageAu(1, ts); stageAu(2, ts); stageAu(3, ts);
        stageBu(0, ts); stageBu(1, ts); stageBu(2, ts);
    };

    f32x4 acc[8][3] = {};
    stageTile(0); stageTile(1);
    asm volatile("s_waitcnt vmcnt(7)" ::: "memory");
    __builtin_amdgcn_s_barrier();

    half8 a[4][2], b[3][2];
    for (int tau = 0; tau < TAU; ++tau) {
        const _Float16* Ab = &Al[tau & 1][0];
        const _Float16* Bb = &Bl[tau & 1][0];
        const bool t2 = (tau + 2 < TAU);

        // ---- p0: ds a-half0 + all b ; bar ; MFMA h0 x {n0,n1} ----
#pragma unroll
        for (int m = 0; m < 4; ++m)
#pragma unroll
            for (int ks = 0; ks < 2; ++ks) {
                int r = wm * 128 + m * 16 + l15;
                a[m][ks] = *(const half8*)(Ab + r * 64 + (((ks * 4 + l4) ^ (r & 7)) * 8));
            }
#pragma unroll
        for (int n = 0; n < 3; ++n)
#pragma unroll
            for (int ks = 0; ks < 2; ++ks) {
                int r = wn * 48 + n * 16 + l15;
                b[n][ks] = *(const half8*)(Bb + r * 64 + (((ks * 4 + l4) ^ (r & 7)) * 8));
            }
        __builtin_amdgcn_s_barrier();
        __builtin_amdgcn_s_setprio(1);
#pragma unroll
        for (int m = 0; m < 4; ++m)
#pragma unroll
            for (int n = 0; n < 2; ++n)
#pragma unroll
                for (int ks = 0; ks < 2; ++ks)
                    acc[m][n] = __builtin_amdgcn_mfma_f32_16x16x32_f16(a[m][ks], b[n][ks], acc[m][n], 0, 0, 0);
        __builtin_amdgcn_s_setprio(0);
        __builtin_amdgcn_s_barrier();

        // ---- p1: stage B units (tau+2) ; bar ; MFMA h0 x n2 ----
        if (t2) { stageBu(0, tau + 2); stageBu(1, tau + 2); stageBu(2, tau + 2); }
        __builtin_amdgcn_s_barrier();
        __builtin_amdgcn_s_setprio(1);
#pragma unroll
        for (int m = 0; m < 4; ++m)
#pragma unroll
            for (int ks = 0; ks < 2; ++ks)
                acc[m][2] = __builtin_amdgcn_mfma_f32_16x16x32_f16(a[m][ks], b[2][ks], acc[m][2], 0, 0, 0);
        __builtin_amdgcn_s_setprio(0);
        __builtin_amdgcn_s_barrier();

        // ---- p2: ds a-half1 ; stage A units 0,2 ; bar ; MFMA h1 x {n0,n1} ----
#pragma unroll
        for (int m = 0; m < 4; ++m)
#pragma unroll
            for (int ks = 0; ks < 2; ++ks) {
                int r = wm * 128 + 64 + m * 16 + l15;
                a[m][ks] = *(const half8*)(Ab + r * 64 + (((ks * 4 + l4) ^ (r & 7)) * 8));
            }
        if (t2) { stageAu(0, tau + 2); stageAu(2, tau + 2); }
        __builtin_amdgcn_s_barrier();
        __builtin_amdgcn_s_setprio(1);
#pragma unroll
        for (int m = 0; m < 4; ++m)
#pragma unroll
            for (int n = 0; n < 2; ++n)
#pragma unroll
                for (int ks = 0; ks < 2; ++ks)
                    acc[4 + m][n] = __builtin_amdgcn_mfma_f32_16x16x32_f16(a[m][ks], b[n][ks], acc[4 + m][n], 0, 0, 0);
        __builtin_amdgcn_s_setprio(0);
        __builtin_amdgcn_s_barrier();

        // ---- p3: stage A units 1,3 ; bar ; MFMA h1 x n2 ; vmcnt ; bar ----
        if (t2) { stageAu(1, tau + 2); stageAu(3, tau + 2); }
        __builtin_amdgcn_s_barrier();
        __builtin_amdgcn_s_setprio(1);
#pragma unroll
        for (int m = 0; m < 4; ++m)
#pragma unroll
            for (int ks = 0; ks < 2; ++ks)
                acc[4 + m][2] = __builtin_amdgcn_mfma_f32_16x16x32_f16(a[m][ks], b[2][ks], acc[4 + m][2], 0, 0, 0);
        __builtin_amdgcn_s_setprio(0);
        if (tau <= TAU - 3) {
            asm volatile("s_waitcnt vmcnt(7)" ::: "memory");
        } else if (tau == TAU - 2) {
            asm volatile("s_waitcnt vmcnt(0)" ::: "memory");
        }
        __builtin_amdgcn_s_barrier();
    }

#pragma unroll
    for (int mi = 0; mi < 8; ++mi)
#pragma unroll
        for (int ni = 0; ni < 3; ++ni)
#pragma unroll
            for (int j = 0; j < 4; ++j) {
                int r = row0 + wm * 128 + (mi >> 2) * 64 + (mi & 3) * 16 + l4 * 4 + j;
                int c = col0 + wn * 48 + ni * 16 + l15;
                store1(C + (size_t)r * N + c, acc[mi][ni][j]);
            }
}

// ---------- 128^2 GEMM (GEMM2): 2-phase, 16KB LDS (R5 version) ----------
template <typename OutT>
__global__ __launch_bounds__(256, 2) void gemm_h(
    const _Float16* __restrict__ A, const _Float16* __restrict__ Bt,
    OutT* __restrict__ C, int M, int N, int K) {
    __shared__ _Float16 Al[128 * 32];
    __shared__ _Float16 Bl[128 * 32];
    const int tid = threadIdx.x;
    const int wave = tid >> 6, lane = tid & 63;
    const int l15 = lane & 15, l4 = lane >> 4;
    const int gx = gridDim.x;
    int lin = blockIdx.y * gx + blockIdx.x;
    int bcol, brow;
    if ((gx & 7) == 0) {
        int cpx = gx >> 3;
        int xcd = lin & 7;
        int idx = lin >> 3;
        bcol = xcd * cpx + idx % cpx;
        brow = idx / cpx;
    } else { bcol = blockIdx.x; brow = blockIdx.y; }
    const int row0 = brow * 128, col0 = bcol * 128;
    const int wm = wave >> 1, wn = wave & 1;
    f32x4 acc[4][4] = {};
    for (int k0 = 0; k0 < K; k0 += 32) {
#pragma unroll
        for (int i = 0; i < 2; ++i) {
            int c = tid + 256 * i;
            int r = c >> 2, c8 = (c & 3) * 8;
            __builtin_amdgcn_global_load_lds(
                (const __attribute__((address_space(1))) void*)(A + (size_t)(row0 + r) * K + k0 + c8),
                (__attribute__((address_space(3))) void*)(Al + (size_t)(wave * 64 + 256 * i) * 8),
                16, 0, 0);
        }
#pragma unroll
        for (int i = 0; i < 2; ++i) {
            int c = tid + 256 * i;
            int r = c >> 2, c8 = (c & 3) * 8;
            __builtin_amdgcn_global_load_lds(
                (const __attribute__((address_space(1))) void*)(Bt + (size_t)(col0 + r) * K + k0 + c8),
                (__attribute__((address_space(3))) void*)(Bl + (size_t)(wave * 64 + 256 * i) * 8),
                16, 0, 0);
        }
        __syncthreads();
        half8 a[4], b[4];
#pragma unroll
        for (int m = 0; m < 4; ++m)
            a[m] = *(const half8*)(Al + (wm * 64 + m * 16 + l15) * 32 + l4 * 8);
#pragma unroll
        for (int n = 0; n < 4; ++n)
            b[n] = *(const half8*)(Bl + (wn * 64 + n * 16 + l15) * 32 + l4 * 8);
        __builtin_amdgcn_s_setprio(1);
#pragma unroll
        for (int m = 0; m < 4; ++m)
#pragma unroll
            for (int n = 0; n < 4; ++n)
                acc[m][n] = __builtin_amdgcn_mfma_f32_16x16x32_f16(a[m], b[n], acc[m][n], 0, 0, 0);
        __builtin_amdgcn_s_setprio(0);
        __syncthreads();
    }
#pragma unroll
    for (int m = 0; m < 4; ++m)
#pragma unroll
        for (int n = 0; n < 4; ++n)
#pragma unroll
            for (int j = 0; j < 4; ++j) {
                int r = row0 + wm * 64 + m * 16 + l4 * 4 + j;
                int cc = col0 + wn * 64 + n * 16 + l15;
                store1(C + (size_t)r * N + cc, acc[m][n][j]);
            }
}

// ---------- flash attention v7: v4 schedule + compile-time ring index ----------
// grid (1024): qt = 15-(bid>>6), bh = bid&63 (XCD-grouped). 4 waves x 32 q rows.
// KV tiles of 64, 3-buffer ring, counted vmcnt(4). Ring index CUR is a template
// constant (3-way dispatch) so all LDS addresses fold to loop-invariant lane
// registers + ds offset immediates -- attacks the 66% VALUBusy addressing cost.
__global__ __launch_bounds__(256, 3) void attn_kernel(const _Float16* __restrict__ qkv,
                                                      const _Float16* __restrict__ vT,
                                                      _Float16* __restrict__ ao) {
    const int bid = blockIdx.x;
    const int qt = 15 - (bid >> 6);
    const int bh = bid & 63;
    const int b = bh >> 4, h = bh & 15;
    const int tid = threadIdx.x, lane = tid & 63;
    const int wave = tid >> 6;
    const int l31 = lane & 31, L = lane >> 5;

    __shared__ _Float16 Kl[3][64 * 64];
    __shared__ _Float16 Vl[3][64 * 64];

    const float qscale = 0.125f * 1.44269504089f;
    const float NEGC = -4.0f * 1.44269504089f;

    const int q0w = qt * 128 + wave * 32;
    const int q_g = q0w + l31;
    const int nt = 2 * qt + 2;

    // staging lane constants
    const int sk_key = tid >> 3, sk_u = tid & 7;
    const int sk_d8 = (sk_u ^ (sk_key & 7)) * 8;          // K source col
    const int sv_d = tid >> 3;
    const int sv_k8 = (sk_u ^ (sv_d & 7)) * 8;            // V source col

    auto stage = [&](int t, auto bufc) {
        constexpr int BUF = decltype(bufc)::value;
#pragma unroll
        for (int i = 0; i < 2; ++i) {
            int idx = tid + 256 * i;
            int key = idx >> 3;
            int d8 = ((idx & 7) ^ (key & 7)) * 8;
            __builtin_amdgcn_global_load_lds(
                (const __attribute__((address_space(1))) void*)(qkv + (size_t)(b * SEQ + t * 64 + key) * C3 + N_EMBD + h * HD + d8),
                (__attribute__((address_space(3))) void*)(&Kl[BUF][idx * 8]), 16, 0, 0);
        }
#pragma unroll
        for (int i = 0; i < 2; ++i) {
            int idx = tid + 256 * i;
            int d = idx >> 3;
            int k8 = ((idx & 7) ^ (d & 7)) * 8;
            __builtin_amdgcn_global_load_lds(
                (const __attribute__((address_space(1))) void*)(vT + ((size_t)bh * HD + d) * SEQ + t * 64 + k8),
                (__attribute__((address_space(3))) void*)(&Vl[BUF][idx * 8]), 16, 0, 0);
        }
    };

    stage(0, IC<0>{});
    stage(1, IC<1>{});

    half8 qb[4];
#pragma unroll
    for (int ks = 0; ks < 4; ++ks) {
        half8 v = *(const half8*)(qkv + (size_t)(b * SEQ + q_g) * C3 + h * HD + ks * 16 + L * 8);
#pragma unroll
        for (int e = 0; e < 8; ++e) v[e] = (_Float16)((float)v[e] * qscale);
        qb[ks] = v;
    }
    half8 onesf;
#pragma unroll
    for (int e = 0; e < 8; ++e) onesf[e] = (_Float16)1.0f;

    const f32x16 cinit = (f32x16)(NEGC);
    f32x16 o[2];
    o[0] = (f32x16)(0.f);
    o[1] = (f32x16)(0.f);
    f32x16 lac = (f32x16)(0.f);

    asm volatile("s_waitcnt vmcnt(4)" ::: "memory");
    __builtin_amdgcn_s_barrier();

    int c3 = 0;
    for (int t = 0; t < nt; ++t) {
        auto step = [&](auto curc) {
            constexpr int CUR = decltype(curc)::value;
            constexpr int SB = (CUR + 2) % 3;
            const int kv0 = t * 64;
            if (t + 2 < nt) stage(t + 2, IC<SB>{});

            if (kv0 <= q0w + 31) {
                f32x16 s[2];
                __builtin_amdgcn_s_setprio(1);
#pragma unroll
                for (int kb = 0; kb < 2; ++kb) {
                    const int key = kb * 32 + l31;
                    {
                        half8 kf = *(const half8*)(&Kl[CUR][key * 64 + ((L ^ (key & 7)) * 8)]);
                        s[kb] = __builtin_amdgcn_mfma_f32_32x32x16_f16(kf, qb[0], cinit, 0, 0, 0);
                    }
#pragma unroll
                    for (int ks = 1; ks < 4; ++ks) {
                        half8 kf = *(const half8*)(&Kl[CUR][key * 64 + (((ks * 2 + L) ^ (key & 7)) * 8)]);
                        s[kb] = __builtin_amdgcn_mfma_f32_32x32x16_f16(kf, qb[ks], s[kb], 0, 0, 0);
                    }
                }
                __builtin_amdgcn_s_setprio(0);
                const bool needmask = (kv0 + 63 > q0w);
#pragma unroll
                for (int kb = 0; kb < 2; ++kb) {
#pragma unroll
                    for (int r = 0; r < 16; ++r) {
                        float v = exp2f(s[kb][r]);
                        if (needmask) {
                            int key_g = kv0 + kb * 32 + (r & 3) + 8 * (r >> 2) + 4 * L;
                            v = (key_g > q_g) ? 0.f : v;
                        }
                        s[kb][r] = v;
                    }
                }
                half8 paf[4];
#pragma unroll
                for (int kb = 0; kb < 2; ++kb)
#pragma unroll
                    for (int hf = 0; hf < 2; ++hf) {
                        const int bse = hf * 8;
                        uint32_t a0 = pk2(s[kb][bse + 0], s[kb][bse + 1]);
                        uint32_t b0 = pk2(s[kb][bse + 4], s[kb][bse + 5]);
                        swap32(a0, b0);
                        uint32_t a1 = pk2(s[kb][bse + 2], s[kb][bse + 3]);
                        uint32_t b1 = pk2(s[kb][bse + 6], s[kb][bse + 7]);
                        swap32(a1, b1);
                        uint32_t w[4] = {a0, a1, b0, b1};
                        __builtin_memcpy(&paf[kb * 2 + hf], w, 16);
                    }
                __builtin_amdgcn_s_setprio(1);
#pragma unroll
                for (int ks = 0; ks < 4; ++ks) {
                    lac = __builtin_amdgcn_mfma_f32_32x32x16_f16(paf[ks], onesf, lac, 0, 0, 0);
#pragma unroll
                    for (int db = 0; db < 2; ++db) {
                        const int d = db * 32 + l31;
                        half8 vb = *(const half8*)(&Vl[CUR][d * 64 + (((ks * 2 + L) ^ (d & 7)) * 8)]);
                        o[db] = __builtin_amdgcn_mfma_f32_32x32x16_f16(paf[ks], vb, o[db], 0, 0, 0);
                    }
                }
                __builtin_amdgcn_s_setprio(0);
            }

            if (t + 2 < nt) {
                asm volatile("s_waitcnt vmcnt(4)" ::: "memory");
            } else if (t + 1 < nt) {
                asm volatile("s_waitcnt vmcnt(0)" ::: "memory");
            }
            __builtin_amdgcn_s_barrier();
        };
        if (c3 == 0) step(IC<0>{});
        else if (c3 == 1) step(IC<1>{});
        else step(IC<2>{});
        ++c3; if (c3 == 3) c3 = 0;
    }

#pragma unroll
    for (int db = 0; db < 2; ++db)
#pragma unroll
        for (int r = 0; r < 16; ++r) {
            int qg = q0w + (r & 3) + 8 * (r >> 2) + 4 * L;
            ao[(size_t)(b * SEQ + qg) * N_EMBD + h * HD + db * 32 + l31] =
                (_Float16)(o[db][r] / lac[r]);
        }
}

// ---------- launch ----------
extern "C" void kernel_launch(void* const* d_in, const int* in_sizes, int n_in,
                              void* d_out, int out_size, void* d_ws, size_t ws_size,
                              hipStream_t stream) {
    const float* x  = (const float*)d_in[0];   // [B,T,C]
    const float* Wa = (const float*)d_in[1];   // [C, 3C]
    const float* Wp = (const float*)d_in[2];   // [C, C]
    float* out = (float*)d_out;                // [B,T,C]

    const int M = BATCH * SEQ;                 // 8192
    _Float16* xh  = (_Float16*)d_ws;           // M*C (dead after GEMM1; reused as vT)
    _Float16* WaT = xh + (size_t)M * N_EMBD;                 // [3C][C]
    _Float16* WpT = WaT + (size_t)C3 * N_EMBD;               // [C][C]
    _Float16* qkv = WpT + (size_t)N_EMBD * N_EMBD;           // [M][3C]
    _Float16* ao  = qkv + (size_t)M * C3;                    // [M][C]
    _Float16* vT  = xh;                                      // [64][64][SEQ], aliases xh

    int nx = M * N_EMBD;
    cvt_f32_f16<<<nx / 4 / 256, 256, 0, stream>>>(x, xh, nx);
    dim3 tb(32, 8);
    transpose_cvt<<<dim3(C3 / 32, N_EMBD / 32), tb, 0, stream>>>(Wa, WaT, N_EMBD, C3);
    transpose_cvt<<<dim3(N_EMBD / 32, N_EMBD / 32), tb, 0, stream>>>(Wp, WpT, N_EMBD, N_EMBD);

    gemm192<_Float16><<<dim3((M / 256) * (C3 / 192)), 512, 0, stream>>>(xh, WaT, qkv, M, C3, N_EMBD);

    transpose_v<<<dim3(SEQ / 32, BATCH * N_HEADS * 2), tb, 0, stream>>>(qkv, vT);

    attn_kernel<<<dim3(1024), 256, 0, stream>>>(qkv, vT, ao);

    gemm_h<float><<<dim3(N_EMBD / 128, M / 128), 256, 0, stream>>>(ao, WpT, out, M, N_EMBD, N_EMBD);
}

// Round 9
// 188.128 us; speedup vs baseline: 1.3942x; 1.3942x over previous
//
#include <hip/hip_runtime.h>
#include <cstddef>
#include <cstdint>

// ---------- types ----------
typedef __attribute__((ext_vector_type(8))) _Float16 half8;
typedef __attribute__((ext_vector_type(4))) _Float16 half4;
typedef __attribute__((ext_vector_type(4))) float f32x4;
typedef __attribute__((ext_vector_type(16))) float f32x16;

#define N_EMBD 1024
#define N_HEADS 16
#define BATCH 4
#define SEQ 2048
#define C3 3072
#define HD 64

__device__ inline uint32_t pk2(float x, float y) {
    auto h2 = __builtin_amdgcn_cvt_pkrtz(x, y);
    uint32_t u;
    __builtin_memcpy(&u, &h2, 4);
    return u;
}

__device__ inline void swap32(uint32_t& a, uint32_t& b) {
    asm volatile("v_permlane32_swap_b32 %0, %1" : "+v"(a), "+v"(b));
}

__device__ inline float exp2_hw(float x) {
    float r;
    asm("v_exp_f32 %0, %1" : "=v"(r) : "v"(x));
    return r;
}

// ---------- fp32 -> fp16 convert ----------
__global__ void cvt_f32_f16(const float* __restrict__ in, _Float16* __restrict__ out, int n) {
    int i = (blockIdx.x * 256 + threadIdx.x) * 4;
    if (i >= n) return;
    float4 v = *(const float4*)(in + i);
    half4 h;
    h[0] = (_Float16)v.x; h[1] = (_Float16)v.y; h[2] = (_Float16)v.z; h[3] = (_Float16)v.w;
    *(half4*)(out + i) = h;
}

// ---------- transpose + convert: in[R][Ncols] f32 -> out[Ncols][R] f16 ----------
__global__ void transpose_cvt(const float* __restrict__ in, _Float16* __restrict__ out,
                              int R, int Ncols) {
    __shared__ float tile[32][33];
    int n0 = blockIdx.x * 32, r0 = blockIdx.y * 32;
    int tx = threadIdx.x, ty = threadIdx.y;  // 32 x 8
#pragma unroll
    for (int i = 0; i < 32; i += 8)
        tile[ty + i][tx] = in[(size_t)(r0 + ty + i) * Ncols + n0 + tx];
    __syncthreads();
#pragma unroll
    for (int i = 0; i < 32; i += 8)
        out[(size_t)(n0 + ty + i) * R + r0 + tx] = (_Float16)tile[tx][ty + i];
}

// ---------- V transpose: qkv V-part [T][64] -> vT[bh][64][T] (f16) ----------
__global__ void transpose_v(const _Float16* __restrict__ qkv, _Float16* __restrict__ vT) {
    __shared__ _Float16 tile[32][36];
    int t0 = blockIdx.x * 32;
    int bhd = blockIdx.y;           // bh*2 + dh
    int bh = bhd >> 1, dh = bhd & 1;
    int b = bh >> 4, h = bh & 15;
    int tx = threadIdx.x, ty = threadIdx.y;  // 32 x 8
#pragma unroll
    for (int i = 0; i < 32; i += 8)
        tile[ty + i][tx] = qkv[(size_t)(b * SEQ + t0 + ty + i) * C3 + 2 * N_EMBD + h * HD + dh * 32 + tx];
    __syncthreads();
#pragma unroll
    for (int i = 0; i < 32; i += 8)
        vT[((size_t)bh * HD + dh * 32 + ty + i) * SEQ + t0 + tx] = tile[tx][ty + i];
}

__device__ inline void store1(float* p, float v) { *p = v; }
__device__ inline void store1(_Float16* p, float v) { *p = (_Float16)v; }

// ---------- 256x192 4-phase GEMM (GEMM1): grid 512 = exactly 2 rounds ----------
template <typename OutT>
__global__ __launch_bounds__(512, 1) void gemm192(
    const _Float16* __restrict__ A, const _Float16* __restrict__ Bt,
    OutT* __restrict__ C, int M, int N, int K) {
    __shared__ _Float16 Al[2][256 * 64];
    __shared__ _Float16 Bl[2][192 * 64];
    const int tid = threadIdx.x;
    const int lane = tid & 63, wave = tid >> 6;
    const int l15 = lane & 15, l4 = lane >> 4;
    const int wm = wave >> 2, wn = wave & 3;

    const int nwg = gridDim.x, nbx = N / 192;
    int wg = blockIdx.x;
    if ((nwg & 7) == 0) { int cpx = nwg >> 3; wg = (wg & 7) * cpx + (wg >> 3); }
    const int row0 = (wg / nbx) * 256, col0 = (wg % nbx) * 192;
    const int TAU = K >> 6;

    const int srow = tid >> 3, su = tid & 7;
    const int usrc8 = (su ^ (srow & 7)) * 8;
    auto stageAu = [&](int unit, int ts) {
        __builtin_amdgcn_global_load_lds(
            (const __attribute__((address_space(1))) void*)(A + (size_t)(row0 + unit * 64 + srow) * K + ts * 64 + usrc8),
            (__attribute__((address_space(3))) void*)(&Al[ts & 1][unit * 64 * 64 + tid * 8]), 16, 0, 0);
    };
    auto stageBu = [&](int unit, int ts) {
        __builtin_amdgcn_global_load_lds(
            (const __attribute__((address_space(1))) void*)(Bt + (size_t)(col0 + unit * 64 + srow) * K + ts * 64 + usrc8),
            (__attribute__((address_space(3))) void*)(&Bl[ts & 1][unit * 64 * 64 + tid * 8]), 16, 0, 0);
    };
    auto stageTile = [&](int ts) {
        stageAu(0, ts); stageAu(1, ts); stageAu(2, ts); stageAu(3, ts);
        stageBu(0, ts); stageBu(1, ts); stageBu(2, ts);
    };

    f32x4 acc[8][3] = {};
    stageTile(0); stageTile(1);
    asm volatile("s_waitcnt vmcnt(7)" ::: "memory");
    __builtin_amdgcn_s_barrier();

    half8 a[4][2], b[3][2];
    for (int tau = 0; tau < TAU; ++tau) {
        const _Float16* Ab = &Al[tau & 1][0];
        const _Float16* Bb = &Bl[tau & 1][0];
        const bool t2 = (tau + 2 < TAU);

        // ---- p0: ds a-half0 + all b ; bar ; MFMA h0 x {n0,n1} ----
#pragma unroll
        for (int m = 0; m < 4; ++m)
#pragma unroll
            for (int ks = 0; ks < 2; ++ks) {
                int r = wm * 128 + m * 16 + l15;
                a[m][ks] = *(const half8*)(Ab + r * 64 + (((ks * 4 + l4) ^ (r & 7)) * 8));
            }
#pragma unroll
        for (int n = 0; n < 3; ++n)
#pragma unroll
            for (int ks = 0; ks < 2; ++ks) {
                int r = wn * 48 + n * 16 + l15;
                b[n][ks] = *(const half8*)(Bb + r * 64 + (((ks * 4 + l4) ^ (r & 7)) * 8));
            }
        __builtin_amdgcn_s_barrier();
        __builtin_amdgcn_s_setprio(1);
#pragma unroll
        for (int m = 0; m < 4; ++m)
#pragma unroll
            for (int n = 0; n < 2; ++n)
#pragma unroll
                for (int ks = 0; ks < 2; ++ks)
                    acc[m][n] = __builtin_amdgcn_mfma_f32_16x16x32_f16(a[m][ks], b[n][ks], acc[m][n], 0, 0, 0);
        __builtin_amdgcn_s_setprio(0);
        __builtin_amdgcn_s_barrier();

        // ---- p1: stage B units (tau+2) ; bar ; MFMA h0 x n2 ----
        if (t2) { stageBu(0, tau + 2); stageBu(1, tau + 2); stageBu(2, tau + 2); }
        __builtin_amdgcn_s_barrier();
        __builtin_amdgcn_s_setprio(1);
#pragma unroll
        for (int m = 0; m < 4; ++m)
#pragma unroll
            for (int ks = 0; ks < 2; ++ks)
                acc[m][2] = __builtin_amdgcn_mfma_f32_16x16x32_f16(a[m][ks], b[2][ks], acc[m][2], 0, 0, 0);
        __builtin_amdgcn_s_setprio(0);
        __builtin_amdgcn_s_barrier();

        // ---- p2: ds a-half1 ; stage A units 0,2 ; bar ; MFMA h1 x {n0,n1} ----
#pragma unroll
        for (int m = 0; m < 4; ++m)
#pragma unroll
            for (int ks = 0; ks < 2; ++ks) {
                int r = wm * 128 + 64 + m * 16 + l15;
                a[m][ks] = *(const half8*)(Ab + r * 64 + (((ks * 4 + l4) ^ (r & 7)) * 8));
            }
        if (t2) { stageAu(0, tau + 2); stageAu(2, tau + 2); }
        __builtin_amdgcn_s_barrier();
        __builtin_amdgcn_s_setprio(1);
#pragma unroll
        for (int m = 0; m < 4; ++m)
#pragma unroll
            for (int n = 0; n < 2; ++n)
#pragma unroll
                for (int ks = 0; ks < 2; ++ks)
                    acc[4 + m][n] = __builtin_amdgcn_mfma_f32_16x16x32_f16(a[m][ks], b[n][ks], acc[4 + m][n], 0, 0, 0);
        __builtin_amdgcn_s_setprio(0);
        __builtin_amdgcn_s_barrier();

        // ---- p3: stage A units 1,3 ; bar ; MFMA h1 x n2 ; vmcnt ; bar ----
        if (t2) { stageAu(1, tau + 2); stageAu(3, tau + 2); }
        __builtin_amdgcn_s_barrier();
        __builtin_amdgcn_s_setprio(1);
#pragma unroll
        for (int m = 0; m < 4; ++m)
#pragma unroll
            for (int ks = 0; ks < 2; ++ks)
                acc[4 + m][2] = __builtin_amdgcn_mfma_f32_16x16x32_f16(a[m][ks], b[2][ks], acc[4 + m][2], 0, 0, 0);
        __builtin_amdgcn_s_setprio(0);
        if (tau <= TAU - 3) {
            asm volatile("s_waitcnt vmcnt(7)" ::: "memory");
        } else if (tau == TAU - 2) {
            asm volatile("s_waitcnt vmcnt(0)" ::: "memory");
        }
        __builtin_amdgcn_s_barrier();
    }

#pragma unroll
    for (int mi = 0; mi < 8; ++mi)
#pragma unroll
        for (int ni = 0; ni < 3; ++ni)
#pragma unroll
            for (int j = 0; j < 4; ++j) {
                int r = row0 + wm * 128 + (mi >> 2) * 64 + (mi & 3) * 16 + l4 * 4 + j;
                int c = col0 + wn * 48 + ni * 16 + l15;
                store1(C + (size_t)r * N + c, acc[mi][ni][j]);
            }
}

// ---------- 128^2 GEMM (GEMM2): 2-phase, 16KB LDS ----------
template <typename OutT>
__global__ __launch_bounds__(256, 2) void gemm_h(
    const _Float16* __restrict__ A, const _Float16* __restrict__ Bt,
    OutT* __restrict__ C, int M, int N, int K) {
    __shared__ _Float16 Al[128 * 32];
    __shared__ _Float16 Bl[128 * 32];
    const int tid = threadIdx.x;
    const int wave = tid >> 6, lane = tid & 63;
    const int l15 = lane & 15, l4 = lane >> 4;
    const int gx = gridDim.x;
    int lin = blockIdx.y * gx + blockIdx.x;
    int bcol, brow;
    if ((gx & 7) == 0) {
        int cpx = gx >> 3;
        int xcd = lin & 7;
        int idx = lin >> 3;
        bcol = xcd * cpx + idx % cpx;
        brow = idx / cpx;
    } else { bcol = blockIdx.x; brow = blockIdx.y; }
    const int row0 = brow * 128, col0 = bcol * 128;
    const int wm = wave >> 1, wn = wave & 1;
    f32x4 acc[4][4] = {};
    for (int k0 = 0; k0 < K; k0 += 32) {
#pragma unroll
        for (int i = 0; i < 2; ++i) {
            int c = tid + 256 * i;
            int r = c >> 2, c8 = (c & 3) * 8;
            __builtin_amdgcn_global_load_lds(
                (const __attribute__((address_space(1))) void*)(A + (size_t)(row0 + r) * K + k0 + c8),
                (__attribute__((address_space(3))) void*)(Al + (size_t)(wave * 64 + 256 * i) * 8),
                16, 0, 0);
        }
#pragma unroll
        for (int i = 0; i < 2; ++i) {
            int c = tid + 256 * i;
            int r = c >> 2, c8 = (c & 3) * 8;
            __builtin_amdgcn_global_load_lds(
                (const __attribute__((address_space(1))) void*)(Bt + (size_t)(col0 + r) * K + k0 + c8),
                (__attribute__((address_space(3))) void*)(Bl + (size_t)(wave * 64 + 256 * i) * 8),
                16, 0, 0);
        }
        __syncthreads();
        half8 a[4], b[4];
#pragma unroll
        for (int m = 0; m < 4; ++m)
            a[m] = *(const half8*)(Al + (wm * 64 + m * 16 + l15) * 32 + l4 * 8);
#pragma unroll
        for (int n = 0; n < 4; ++n)
            b[n] = *(const half8*)(Bl + (wn * 64 + n * 16 + l15) * 32 + l4 * 8);
        __builtin_amdgcn_s_setprio(1);
#pragma unroll
        for (int m = 0; m < 4; ++m)
#pragma unroll
            for (int n = 0; n < 4; ++n)
                acc[m][n] = __builtin_amdgcn_mfma_f32_16x16x32_f16(a[m], b[n], acc[m][n], 0, 0, 0);
        __builtin_amdgcn_s_setprio(0);
        __syncthreads();
    }
#pragma unroll
    for (int m = 0; m < 4; ++m)
#pragma unroll
        for (int n = 0; n < 4; ++n)
#pragma unroll
            for (int j = 0; j < 4; ++j) {
                int r = row0 + wm * 64 + m * 16 + l4 * 4 + j;
                int cc = col0 + wn * 64 + n * 16 + l15;
                store1(C + (size_t)r * N + cc, acc[m][n][j]);
            }
}

// ---------- flash attention v8: v4 schedule, 8-wave blocks sharing the ring ----------
// grid (512) x 512 threads: 8 waves x 32 q rows = 256 q rows/block. qt8 mapping
// makes CU-paired blocks (bid, bid+256) sum to uniform 36 steps. 3-buffer ring
// (48KB), counted vmcnt(2) (2 loads/thread/stage), runtime ring index (R8's
// compile-time version spilled). All 512 blocks co-resident: 16 waves/CU.
__global__ __launch_bounds__(512, 4) void attn_kernel(const _Float16* __restrict__ qkv,
                                                      const _Float16* __restrict__ vT,
                                                      _Float16* __restrict__ ao) {
    const int bid = blockIdx.x;
    const int qt8 = (bid < 256) ? (bid >> 6) : 7 - ((bid - 256) >> 6);
    const int bh = bid & 63;
    const int b = bh >> 4, h = bh & 15;
    const int tid = threadIdx.x, lane = tid & 63;
    const int wave = tid >> 6;           // 0..7
    const int l31 = lane & 31, L = lane >> 5;

    __shared__ _Float16 Kl[3][64 * 64];
    __shared__ _Float16 Vl[3][64 * 64];

    const float qscale = 0.125f * 1.44269504089f;
    const float NEGC = -4.0f * 1.44269504089f;

    const int q0w = qt8 * 256 + wave * 32;
    const int q_g = q0w + l31;
    const int nt = 4 * qt8 + 4;

    // staging: 512 threads -> 1 K-load + 1 V-load each (16B), source pre-swizzled
    const int s_row = tid >> 3;                       // key (K) or d (V), 0..63
    const int s_u8 = ((tid & 7) ^ (s_row & 7)) * 8;
    auto stage = [&](int t, int buf) {
        __builtin_amdgcn_global_load_lds(
            (const __attribute__((address_space(1))) void*)(qkv + (size_t)(b * SEQ + t * 64 + s_row) * C3 + N_EMBD + h * HD + s_u8),
            (__attribute__((address_space(3))) void*)(&Kl[buf][tid * 8]), 16, 0, 0);
        __builtin_amdgcn_global_load_lds(
            (const __attribute__((address_space(1))) void*)(vT + ((size_t)bh * HD + s_row) * SEQ + t * 64 + s_u8),
            (__attribute__((address_space(3))) void*)(&Vl[buf][tid * 8]), 16, 0, 0);
    };

    stage(0, 0);
    stage(1, 1);

    half8 qb[4];
#pragma unroll
    for (int ks = 0; ks < 4; ++ks) {
        half8 v = *(const half8*)(qkv + (size_t)(b * SEQ + q_g) * C3 + h * HD + ks * 16 + L * 8);
#pragma unroll
        for (int e = 0; e < 8; ++e) v[e] = (_Float16)((float)v[e] * qscale);
        qb[ks] = v;
    }
    half8 onesf;
#pragma unroll
    for (int e = 0; e < 8; ++e) onesf[e] = (_Float16)1.0f;

    const f32x16 cinit = (f32x16)(NEGC);
    f32x16 o[2];
    o[0] = (f32x16)(0.f);
    o[1] = (f32x16)(0.f);
    f32x16 lac = (f32x16)(0.f);

    asm volatile("s_waitcnt vmcnt(6)" ::: "memory");  // tile 0 landed (tile1 + qb in flight)
    __builtin_amdgcn_s_barrier();

    int cur = 0;
    for (int t = 0; t < nt; ++t) {
        const int kv0 = t * 64;
        int sb = cur + 2; if (sb >= 3) sb -= 3;
        if (t + 2 < nt) stage(t + 2, sb);

        if (kv0 <= q0w + 31) {
            const _Float16* Kb = &Kl[cur][0];
            const _Float16* Vb = &Vl[cur][0];
            f32x16 s[2];
            __builtin_amdgcn_s_setprio(1);
#pragma unroll
            for (int kb = 0; kb < 2; ++kb) {
                const int key = kb * 32 + l31;
                {
                    half8 kf = *(const half8*)(Kb + key * 64 + ((L ^ (key & 7)) * 8));
                    s[kb] = __builtin_amdgcn_mfma_f32_32x32x16_f16(kf, qb[0], cinit, 0, 0, 0);
                }
#pragma unroll
                for (int ks = 1; ks < 4; ++ks) {
                    half8 kf = *(const half8*)(Kb + key * 64 + (((ks * 2 + L) ^ (key & 7)) * 8));
                    s[kb] = __builtin_amdgcn_mfma_f32_32x32x16_f16(kf, qb[ks], s[kb], 0, 0, 0);
                }
            }
            __builtin_amdgcn_s_setprio(0);
            const bool needmask = (kv0 + 63 > q0w);
#pragma unroll
            for (int kb = 0; kb < 2; ++kb) {
#pragma unroll
                for (int r = 0; r < 16; ++r) {
                    float v = exp2_hw(s[kb][r]);
                    if (needmask) {
                        int key_g = kv0 + kb * 32 + (r & 3) + 8 * (r >> 2) + 4 * L;
                        v = (key_g > q_g) ? 0.f : v;
                    }
                    s[kb][r] = v;
                }
            }
            half8 paf[4];
#pragma unroll
            for (int kb = 0; kb < 2; ++kb)
#pragma unroll
                for (int hf = 0; hf < 2; ++hf) {
                    const int bse = hf * 8;
                    uint32_t a0 = pk2(s[kb][bse + 0], s[kb][bse + 1]);
                    uint32_t b0 = pk2(s[kb][bse + 4], s[kb][bse + 5]);
                    swap32(a0, b0);
                    uint32_t a1 = pk2(s[kb][bse + 2], s[kb][bse + 3]);
                    uint32_t b1 = pk2(s[kb][bse + 6], s[kb][bse + 7]);
                    swap32(a1, b1);
                    uint32_t w[4] = {a0, a1, b0, b1};
                    __builtin_memcpy(&paf[kb * 2 + hf], w, 16);
                }
            __builtin_amdgcn_s_setprio(1);
#pragma unroll
            for (int ks = 0; ks < 4; ++ks) {
                lac = __builtin_amdgcn_mfma_f32_32x32x16_f16(paf[ks], onesf, lac, 0, 0, 0);
#pragma unroll
                for (int db = 0; db < 2; ++db) {
                    const int d = db * 32 + l31;
                    half8 vb = *(const half8*)(Vb + d * 64 + (((ks * 2 + L) ^ (d & 7)) * 8));
                    o[db] = __builtin_amdgcn_mfma_f32_32x32x16_f16(paf[ks], vb, o[db], 0, 0, 0);
                }
            }
            __builtin_amdgcn_s_setprio(0);
        }

        if (t + 2 < nt) {
            asm volatile("s_waitcnt vmcnt(2)" ::: "memory");  // t+1 landed, t+2 in flight
        } else if (t + 1 < nt) {
            asm volatile("s_waitcnt vmcnt(0)" ::: "memory");
        }
        __builtin_amdgcn_s_barrier();
        ++cur; if (cur == 3) cur = 0;
    }

#pragma unroll
    for (int db = 0; db < 2; ++db)
#pragma unroll
        for (int r = 0; r < 16; ++r) {
            int qg = q0w + (r & 3) + 8 * (r >> 2) + 4 * L;
            ao[(size_t)(b * SEQ + qg) * N_EMBD + h * HD + db * 32 + l31] =
                (_Float16)(o[db][r] / lac[r]);
        }
}

// ---------- launch ----------
extern "C" void kernel_launch(void* const* d_in, const int* in_sizes, int n_in,
                              void* d_out, int out_size, void* d_ws, size_t ws_size,
                              hipStream_t stream) {
    const float* x  = (const float*)d_in[0];   // [B,T,C]
    const float* Wa = (const float*)d_in[1];   // [C, 3C]
    const float* Wp = (const float*)d_in[2];   // [C, C]
    float* out = (float*)d_out;                // [B,T,C]

    const int M = BATCH * SEQ;                 // 8192
    _Float16* xh  = (_Float16*)d_ws;           // M*C (dead after GEMM1; reused as vT)
    _Float16* WaT = xh + (size_t)M * N_EMBD;                 // [3C][C]
    _Float16* WpT = WaT + (size_t)C3 * N_EMBD;               // [C][C]
    _Float16* qkv = WpT + (size_t)N_EMBD * N_EMBD;           // [M][3C]
    _Float16* ao  = qkv + (size_t)M * C3;                    // [M][C]
    _Float16* vT  = xh;                                      // [64][64][SEQ], aliases xh

    int nx = M * N_EMBD;
    cvt_f32_f16<<<nx / 4 / 256, 256, 0, stream>>>(x, xh, nx);
    dim3 tb(32, 8);
    transpose_cvt<<<dim3(C3 / 32, N_EMBD / 32), tb, 0, stream>>>(Wa, WaT, N_EMBD, C3);
    transpose_cvt<<<dim3(N_EMBD / 32, N_EMBD / 32), tb, 0, stream>>>(Wp, WpT, N_EMBD, N_EMBD);

    gemm192<_Float16><<<dim3((M / 256) * (C3 / 192)), 512, 0, stream>>>(xh, WaT, qkv, M, C3, N_EMBD);

    transpose_v<<<dim3(SEQ / 32, BATCH * N_HEADS * 2), tb, 0, stream>>>(qkv, vT);

    attn_kernel<<<dim3(512), 512, 0, stream>>>(qkv, vT, ao);

    gemm_h<float><<<dim3(N_EMBD / 128, M / 128), 256, 0, stream>>>(ao, WpT, out, M, N_EMBD, N_EMBD);
}

// Round 10
// 187.480 us; speedup vs baseline: 1.3990x; 1.0035x over previous
//
#include <hip/hip_runtime.h>
#include <cstddef>
#include <cstdint>

// ---------- types ----------
typedef __attribute__((ext_vector_type(8))) _Float16 half8;
typedef __attribute__((ext_vector_type(4))) _Float16 half4;
typedef __attribute__((ext_vector_type(4))) float f32x4;
typedef __attribute__((ext_vector_type(16))) float f32x16;

#define N_EMBD 1024
#define N_HEADS 16
#define BATCH 4
#define SEQ 2048
#define C3 3072
#define HD 64

__device__ inline uint32_t pk2(float x, float y) {
    auto h2 = __builtin_amdgcn_cvt_pkrtz(x, y);
    uint32_t u;
    __builtin_memcpy(&u, &h2, 4);
    return u;
}

__device__ inline void swap32(uint32_t& a, uint32_t& b) {
    asm volatile("v_permlane32_swap_b32 %0, %1" : "+v"(a), "+v"(b));
}

__device__ inline float exp2_hw(float x) {
    float r;
    asm("v_exp_f32 %0, %1" : "=v"(r) : "v"(x));
    return r;
}

// ---------- fp32 -> fp16 convert ----------
__global__ void cvt_f32_f16(const float* __restrict__ in, _Float16* __restrict__ out, int n) {
    int i = (blockIdx.x * 256 + threadIdx.x) * 4;
    if (i >= n) return;
    float4 v = *(const float4*)(in + i);
    half4 h;
    h[0] = (_Float16)v.x; h[1] = (_Float16)v.y; h[2] = (_Float16)v.z; h[3] = (_Float16)v.w;
    *(half4*)(out + i) = h;
}

// ---------- transpose + convert: in[R][Ncols] f32 -> out[Ncols][R] f16 ----------
__global__ void transpose_cvt(const float* __restrict__ in, _Float16* __restrict__ out,
                              int R, int Ncols) {
    __shared__ float tile[32][33];
    int n0 = blockIdx.x * 32, r0 = blockIdx.y * 32;
    int tx = threadIdx.x, ty = threadIdx.y;  // 32 x 8
#pragma unroll
    for (int i = 0; i < 32; i += 8)
        tile[ty + i][tx] = in[(size_t)(r0 + ty + i) * Ncols + n0 + tx];
    __syncthreads();
#pragma unroll
    for (int i = 0; i < 32; i += 8)
        out[(size_t)(n0 + ty + i) * R + r0 + tx] = (_Float16)tile[tx][ty + i];
}

// ---------- V transpose: qkv V-part [T][64] -> vT[bh][64][T] (f16) ----------
__global__ void transpose_v(const _Float16* __restrict__ qkv, _Float16* __restrict__ vT) {
    __shared__ _Float16 tile[32][36];
    int t0 = blockIdx.x * 32;
    int bhd = blockIdx.y;           // bh*2 + dh
    int bh = bhd >> 1, dh = bhd & 1;
    int b = bh >> 4, h = bh & 15;
    int tx = threadIdx.x, ty = threadIdx.y;  // 32 x 8
#pragma unroll
    for (int i = 0; i < 32; i += 8)
        tile[ty + i][tx] = qkv[(size_t)(b * SEQ + t0 + ty + i) * C3 + 2 * N_EMBD + h * HD + dh * 32 + tx];
    __syncthreads();
#pragma unroll
    for (int i = 0; i < 32; i += 8)
        vT[((size_t)bh * HD + dh * 32 + ty + i) * SEQ + t0 + tx] = tile[tx][ty + i];
}

__device__ inline void store1(float* p, float v) { *p = v; }
__device__ inline void store1(_Float16* p, float v) { *p = (_Float16)v; }

// ---------- 256x192 4-phase GEMM (GEMM1): grid 512 = exactly 2 rounds ----------
template <typename OutT>
__global__ __launch_bounds__(512, 1) void gemm192(
    const _Float16* __restrict__ A, const _Float16* __restrict__ Bt,
    OutT* __restrict__ C, int M, int N, int K) {
    __shared__ _Float16 Al[2][256 * 64];
    __shared__ _Float16 Bl[2][192 * 64];
    const int tid = threadIdx.x;
    const int lane = tid & 63, wave = tid >> 6;
    const int l15 = lane & 15, l4 = lane >> 4;
    const int wm = wave >> 2, wn = wave & 3;

    const int nwg = gridDim.x, nbx = N / 192;
    int wg = blockIdx.x;
    if ((nwg & 7) == 0) { int cpx = nwg >> 3; wg = (wg & 7) * cpx + (wg >> 3); }
    const int row0 = (wg / nbx) * 256, col0 = (wg % nbx) * 192;
    const int TAU = K >> 6;

    const int srow = tid >> 3, su = tid & 7;
    const int usrc8 = (su ^ (srow & 7)) * 8;
    auto stageAu = [&](int unit, int ts) {
        __builtin_amdgcn_global_load_lds(
            (const __attribute__((address_space(1))) void*)(A + (size_t)(row0 + unit * 64 + srow) * K + ts * 64 + usrc8),
            (__attribute__((address_space(3))) void*)(&Al[ts & 1][unit * 64 * 64 + tid * 8]), 16, 0, 0);
    };
    auto stageBu = [&](int unit, int ts) {
        __builtin_amdgcn_global_load_lds(
            (const __attribute__((address_space(1))) void*)(Bt + (size_t)(col0 + unit * 64 + srow) * K + ts * 64 + usrc8),
            (__attribute__((address_space(3))) void*)(&Bl[ts & 1][unit * 64 * 64 + tid * 8]), 16, 0, 0);
    };
    auto stageTile = [&](int ts) {
        stageAu(0, ts); stageAu(1, ts); stageAu(2, ts); stageAu(3, ts);
        stageBu(0, ts); stageBu(1, ts); stageBu(2, ts);
    };

    f32x4 acc[8][3] = {};
    stageTile(0); stageTile(1);
    asm volatile("s_waitcnt vmcnt(7)" ::: "memory");
    __builtin_amdgcn_s_barrier();

    half8 a[4][2], b[3][2];
    for (int tau = 0; tau < TAU; ++tau) {
        const _Float16* Ab = &Al[tau & 1][0];
        const _Float16* Bb = &Bl[tau & 1][0];
        const bool t2 = (tau + 2 < TAU);

        // ---- p0: ds a-half0 + all b ; bar ; MFMA h0 x {n0,n1} ----
#pragma unroll
        for (int m = 0; m < 4; ++m)
#pragma unroll
            for (int ks = 0; ks < 2; ++ks) {
                int r = wm * 128 + m * 16 + l15;
                a[m][ks] = *(const half8*)(Ab + r * 64 + (((ks * 4 + l4) ^ (r & 7)) * 8));
            }
#pragma unroll
        for (int n = 0; n < 3; ++n)
#pragma unroll
            for (int ks = 0; ks < 2; ++ks) {
                int r = wn * 48 + n * 16 + l15;
                b[n][ks] = *(const half8*)(Bb + r * 64 + (((ks * 4 + l4) ^ (r & 7)) * 8));
            }
        __builtin_amdgcn_s_barrier();
        __builtin_amdgcn_s_setprio(1);
#pragma unroll
        for (int m = 0; m < 4; ++m)
#pragma unroll
            for (int n = 0; n < 2; ++n)
#pragma unroll
                for (int ks = 0; ks < 2; ++ks)
                    acc[m][n] = __builtin_amdgcn_mfma_f32_16x16x32_f16(a[m][ks], b[n][ks], acc[m][n], 0, 0, 0);
        __builtin_amdgcn_s_setprio(0);
        __builtin_amdgcn_s_barrier();

        // ---- p1: stage B units (tau+2) ; bar ; MFMA h0 x n2 ----
        if (t2) { stageBu(0, tau + 2); stageBu(1, tau + 2); stageBu(2, tau + 2); }
        __builtin_amdgcn_s_barrier();
        __builtin_amdgcn_s_setprio(1);
#pragma unroll
        for (int m = 0; m < 4; ++m)
#pragma unroll
            for (int ks = 0; ks < 2; ++ks)
                acc[m][2] = __builtin_amdgcn_mfma_f32_16x16x32_f16(a[m][ks], b[2][ks], acc[m][2], 0, 0, 0);
        __builtin_amdgcn_s_setprio(0);
        __builtin_amdgcn_s_barrier();

        // ---- p2: ds a-half1 ; stage A units 0,2 ; bar ; MFMA h1 x {n0,n1} ----
#pragma unroll
        for (int m = 0; m < 4; ++m)
#pragma unroll
            for (int ks = 0; ks < 2; ++ks) {
                int r = wm * 128 + 64 + m * 16 + l15;
                a[m][ks] = *(const half8*)(Ab + r * 64 + (((ks * 4 + l4) ^ (r & 7)) * 8));
            }
        if (t2) { stageAu(0, tau + 2); stageAu(2, tau + 2); }
        __builtin_amdgcn_s_barrier();
        __builtin_amdgcn_s_setprio(1);
#pragma unroll
        for (int m = 0; m < 4; ++m)
#pragma unroll
            for (int n = 0; n < 2; ++n)
#pragma unroll
                for (int ks = 0; ks < 2; ++ks)
                    acc[4 + m][n] = __builtin_amdgcn_mfma_f32_16x16x32_f16(a[m][ks], b[n][ks], acc[4 + m][n], 0, 0, 0);
        __builtin_amdgcn_s_setprio(0);
        __builtin_amdgcn_s_barrier();

        // ---- p3: stage A units 1,3 ; bar ; MFMA h1 x n2 ; vmcnt ; bar ----
        if (t2) { stageAu(1, tau + 2); stageAu(3, tau + 2); }
        __builtin_amdgcn_s_barrier();
        __builtin_amdgcn_s_setprio(1);
#pragma unroll
        for (int m = 0; m < 4; ++m)
#pragma unroll
            for (int ks = 0; ks < 2; ++ks)
                acc[4 + m][2] = __builtin_amdgcn_mfma_f32_16x16x32_f16(a[m][ks], b[2][ks], acc[4 + m][2], 0, 0, 0);
        __builtin_amdgcn_s_setprio(0);
        if (tau <= TAU - 3) {
            asm volatile("s_waitcnt vmcnt(7)" ::: "memory");
        } else if (tau == TAU - 2) {
            asm volatile("s_waitcnt vmcnt(0)" ::: "memory");
        }
        __builtin_amdgcn_s_barrier();
    }

#pragma unroll
    for (int mi = 0; mi < 8; ++mi)
#pragma unroll
        for (int ni = 0; ni < 3; ++ni)
#pragma unroll
            for (int j = 0; j < 4; ++j) {
                int r = row0 + wm * 128 + (mi >> 2) * 64 + (mi & 3) * 16 + l4 * 4 + j;
                int c = col0 + wn * 48 + ni * 16 + l15;
                store1(C + (size_t)r * N + c, acc[mi][ni][j]);
            }
}

// ---------- 128^2 GEMM (GEMM2): 2-phase, 16KB LDS ----------
template <typename OutT>
__global__ __launch_bounds__(256, 2) void gemm_h(
    const _Float16* __restrict__ A, const _Float16* __restrict__ Bt,
    OutT* __restrict__ C, int M, int N, int K) {
    __shared__ _Float16 Al[128 * 32];
    __shared__ _Float16 Bl[128 * 32];
    const int tid = threadIdx.x;
    const int wave = tid >> 6, lane = tid & 63;
    const int l15 = lane & 15, l4 = lane >> 4;
    const int gx = gridDim.x;
    int lin = blockIdx.y * gx + blockIdx.x;
    int bcol, brow;
    if ((gx & 7) == 0) {
        int cpx = gx >> 3;
        int xcd = lin & 7;
        int idx = lin >> 3;
        bcol = xcd * cpx + idx % cpx;
        brow = idx / cpx;
    } else { bcol = blockIdx.x; brow = blockIdx.y; }
    const int row0 = brow * 128, col0 = bcol * 128;
    const int wm = wave >> 1, wn = wave & 1;
    f32x4 acc[4][4] = {};
    for (int k0 = 0; k0 < K; k0 += 32) {
#pragma unroll
        for (int i = 0; i < 2; ++i) {
            int c = tid + 256 * i;
            int r = c >> 2, c8 = (c & 3) * 8;
            __builtin_amdgcn_global_load_lds(
                (const __attribute__((address_space(1))) void*)(A + (size_t)(row0 + r) * K + k0 + c8),
                (__attribute__((address_space(3))) void*)(Al + (size_t)(wave * 64 + 256 * i) * 8),
                16, 0, 0);
        }
#pragma unroll
        for (int i = 0; i < 2; ++i) {
            int c = tid + 256 * i;
            int r = c >> 2, c8 = (c & 3) * 8;
            __builtin_amdgcn_global_load_lds(
                (const __attribute__((address_space(1))) void*)(Bt + (size_t)(col0 + r) * K + k0 + c8),
                (__attribute__((address_space(3))) void*)(Bl + (size_t)(wave * 64 + 256 * i) * 8),
                16, 0, 0);
        }
        __syncthreads();
        half8 a[4], b[4];
#pragma unroll
        for (int m = 0; m < 4; ++m)
            a[m] = *(const half8*)(Al + (wm * 64 + m * 16 + l15) * 32 + l4 * 8);
#pragma unroll
        for (int n = 0; n < 4; ++n)
            b[n] = *(const half8*)(Bl + (wn * 64 + n * 16 + l15) * 32 + l4 * 8);
        __builtin_amdgcn_s_setprio(1);
#pragma unroll
        for (int m = 0; m < 4; ++m)
#pragma unroll
            for (int n = 0; n < 4; ++n)
                acc[m][n] = __builtin_amdgcn_mfma_f32_16x16x32_f16(a[m], b[n], acc[m][n], 0, 0, 0);
        __builtin_amdgcn_s_setprio(0);
        __syncthreads();
    }
#pragma unroll
    for (int m = 0; m < 4; ++m)
#pragma unroll
        for (int n = 0; n < 4; ++n)
#pragma unroll
            for (int j = 0; j < 4; ++j) {
                int r = row0 + wm * 64 + m * 16 + l4 * 4 + j;
                int cc = col0 + wn * 64 + n * 16 + l15;
                store1(C + (size_t)r * N + cc, acc[m][n][j]);
            }
}

// ---------- flash attention v9: v4 schedule, sequential two-pass uniform blocks ----------
// grid (512) x 256 thr (4 waves x 32 q rows). Block p=bid>>6, bh=bid&63 runs
// qt = p then qt = 15-p sequentially: EVERY block = exactly 34 steps (uniform,
// no concurrent-start imbalance -- R9's pairing failed because co-resident
// blocks start together). bh=bid&63 keeps a head's 8 blocks on one XCD.
// Body: 3-buffer ring, counted vmcnt(4), exp2_hw, runtime ring index.
__global__ __launch_bounds__(256, 3) void attn_kernel(const _Float16* __restrict__ qkv,
                                                      const _Float16* __restrict__ vT,
                                                      _Float16* __restrict__ ao) {
    const int bid = blockIdx.x;
    const int pairp = bid >> 6;          // 0..7
    const int bh = bid & 63;
    const int b = bh >> 4, h = bh & 15;
    const int tid = threadIdx.x, lane = tid & 63;
    const int wave = tid >> 6;
    const int l31 = lane & 31, L = lane >> 5;

    __shared__ _Float16 Kl[3][64 * 64];
    __shared__ _Float16 Vl[3][64 * 64];

    const float qscale = 0.125f * 1.44269504089f;
    const float NEGC = -4.0f * 1.44269504089f;

    auto stage = [&](int t, int buf) {
#pragma unroll
        for (int i = 0; i < 2; ++i) {
            int idx = tid + 256 * i;
            int key = idx >> 3;
            int d8 = ((idx & 7) ^ (key & 7)) * 8;
            __builtin_amdgcn_global_load_lds(
                (const __attribute__((address_space(1))) void*)(qkv + (size_t)(b * SEQ + t * 64 + key) * C3 + N_EMBD + h * HD + d8),
                (__attribute__((address_space(3))) void*)(&Kl[buf][idx * 8]), 16, 0, 0);
        }
#pragma unroll
        for (int i = 0; i < 2; ++i) {
            int idx = tid + 256 * i;
            int d = idx >> 3;
            int k8 = ((idx & 7) ^ (d & 7)) * 8;
            __builtin_amdgcn_global_load_lds(
                (const __attribute__((address_space(1))) void*)(vT + ((size_t)bh * HD + d) * SEQ + t * 64 + k8),
                (__attribute__((address_space(3))) void*)(&Vl[buf][idx * 8]), 16, 0, 0);
        }
    };

    half8 onesf;
#pragma unroll
    for (int e = 0; e < 8; ++e) onesf[e] = (_Float16)1.0f;
    const f32x16 cinit = (f32x16)(NEGC);

    for (int pass = 0; pass < 2; ++pass) {
        const int qt = pass ? (15 - pairp) : pairp;
        const int q0w = qt * 128 + wave * 32;
        const int q_g = q0w + l31;
        const int nt = 2 * qt + 2;

        stage(0, 0);
        stage(1, 1);

        half8 qb[4];
#pragma unroll
        for (int ks = 0; ks < 4; ++ks) {
            half8 v = *(const half8*)(qkv + (size_t)(b * SEQ + q_g) * C3 + h * HD + ks * 16 + L * 8);
#pragma unroll
            for (int e = 0; e < 8; ++e) v[e] = (_Float16)((float)v[e] * qscale);
            qb[ks] = v;
        }

        f32x16 o[2];
        o[0] = (f32x16)(0.f);
        o[1] = (f32x16)(0.f);
        f32x16 lac = (f32x16)(0.f);

        asm volatile("s_waitcnt vmcnt(4)" ::: "memory");
        __builtin_amdgcn_s_barrier();

        int cur = 0;
        for (int t = 0; t < nt; ++t) {
            const int kv0 = t * 64;
            int sb = cur + 2; if (sb >= 3) sb -= 3;
            if (t + 2 < nt) stage(t + 2, sb);

            if (kv0 <= q0w + 31) {
                const _Float16* Kb = &Kl[cur][0];
                const _Float16* Vb = &Vl[cur][0];
                f32x16 s[2];
                __builtin_amdgcn_s_setprio(1);
#pragma unroll
                for (int kb = 0; kb < 2; ++kb) {
                    const int key = kb * 32 + l31;
                    {
                        half8 kf = *(const half8*)(Kb + key * 64 + ((L ^ (key & 7)) * 8));
                        s[kb] = __builtin_amdgcn_mfma_f32_32x32x16_f16(kf, qb[0], cinit, 0, 0, 0);
                    }
#pragma unroll
                    for (int ks = 1; ks < 4; ++ks) {
                        half8 kf = *(const half8*)(Kb + key * 64 + (((ks * 2 + L) ^ (key & 7)) * 8));
                        s[kb] = __builtin_amdgcn_mfma_f32_32x32x16_f16(kf, qb[ks], s[kb], 0, 0, 0);
                    }
                }
                __builtin_amdgcn_s_setprio(0);
                const bool needmask = (kv0 + 63 > q0w);
#pragma unroll
                for (int kb = 0; kb < 2; ++kb) {
#pragma unroll
                    for (int r = 0; r < 16; ++r) {
                        float v = exp2_hw(s[kb][r]);
                        if (needmask) {
                            int key_g = kv0 + kb * 32 + (r & 3) + 8 * (r >> 2) + 4 * L;
                            v = (key_g > q_g) ? 0.f : v;
                        }
                        s[kb][r] = v;
                    }
                }
                half8 paf[4];
#pragma unroll
                for (int kb = 0; kb < 2; ++kb)
#pragma unroll
                    for (int hf = 0; hf < 2; ++hf) {
                        const int bse = hf * 8;
                        uint32_t a0 = pk2(s[kb][bse + 0], s[kb][bse + 1]);
                        uint32_t b0 = pk2(s[kb][bse + 4], s[kb][bse + 5]);
                        swap32(a0, b0);
                        uint32_t a1 = pk2(s[kb][bse + 2], s[kb][bse + 3]);
                        uint32_t b1 = pk2(s[kb][bse + 6], s[kb][bse + 7]);
                        swap32(a1, b1);
                        uint32_t w[4] = {a0, a1, b0, b1};
                        __builtin_memcpy(&paf[kb * 2 + hf], w, 16);
                    }
                __builtin_amdgcn_s_setprio(1);
#pragma unroll
                for (int ks = 0; ks < 4; ++ks) {
                    lac = __builtin_amdgcn_mfma_f32_32x32x16_f16(paf[ks], onesf, lac, 0, 0, 0);
#pragma unroll
                    for (int db = 0; db < 2; ++db) {
                        const int d = db * 32 + l31;
                        half8 vb = *(const half8*)(Vb + d * 64 + (((ks * 2 + L) ^ (d & 7)) * 8));
                        o[db] = __builtin_amdgcn_mfma_f32_32x32x16_f16(paf[ks], vb, o[db], 0, 0, 0);
                    }
                }
                __builtin_amdgcn_s_setprio(0);
            }

            if (t + 2 < nt) {
                asm volatile("s_waitcnt vmcnt(4)" ::: "memory");
            } else if (t + 1 < nt) {
                asm volatile("s_waitcnt vmcnt(0)" ::: "memory");
            }
            __builtin_amdgcn_s_barrier();
            ++cur; if (cur == 3) cur = 0;
        }

#pragma unroll
        for (int db = 0; db < 2; ++db)
#pragma unroll
            for (int r = 0; r < 16; ++r) {
                int qg = q0w + (r & 3) + 8 * (r >> 2) + 4 * L;
                ao[(size_t)(b * SEQ + qg) * N_EMBD + h * HD + db * 32 + l31] =
                    (_Float16)(o[db][r] / lac[r]);
            }
    }
}

// ---------- launch ----------
extern "C" void kernel_launch(void* const* d_in, const int* in_sizes, int n_in,
                              void* d_out, int out_size, void* d_ws, size_t ws_size,
                              hipStream_t stream) {
    const float* x  = (const float*)d_in[0];   // [B,T,C]
    const float* Wa = (const float*)d_in[1];   // [C, 3C]
    const float* Wp = (const float*)d_in[2];   // [C, C]
    float* out = (float*)d_out;                // [B,T,C]

    const int M = BATCH * SEQ;                 // 8192
    _Float16* xh  = (_Float16*)d_ws;           // M*C (dead after GEMM1; reused as vT)
    _Float16* WaT = xh + (size_t)M * N_EMBD;                 // [3C][C]
    _Float16* WpT = WaT + (size_t)C3 * N_EMBD;               // [C][C]
    _Float16* qkv = WpT + (size_t)N_EMBD * N_EMBD;           // [M][3C]
    _Float16* ao  = qkv + (size_t)M * C3;                    // [M][C]
    _Float16* vT  = xh;                                      // [64][64][SEQ], aliases xh

    int nx = M * N_EMBD;
    cvt_f32_f16<<<nx / 4 / 256, 256, 0, stream>>>(x, xh, nx);
    dim3 tb(32, 8);
    transpose_cvt<<<dim3(C3 / 32, N_EMBD / 32), tb, 0, stream>>>(Wa, WaT, N_EMBD, C3);
    transpose_cvt<<<dim3(N_EMBD / 32, N_EMBD / 32), tb, 0, stream>>>(Wp, WpT, N_EMBD, N_EMBD);

    gemm192<_Float16><<<dim3((M / 256) * (C3 / 192)), 512, 0, stream>>>(xh, WaT, qkv, M, C3, N_EMBD);

    transpose_v<<<dim3(SEQ / 32, BATCH * N_HEADS * 2), tb, 0, stream>>>(qkv, vT);

    attn_kernel<<<dim3(512), 256, 0, stream>>>(qkv, vT, ao);

    gemm_h<float><<<dim3(N_EMBD / 128, M / 128), 256, 0, stream>>>(ao, WpT, out, M, N_EMBD, N_EMBD);
}

// Round 11
// 184.859 us; speedup vs baseline: 1.4189x; 1.0142x over previous
//
#include <hip/hip_runtime.h>
#include <cstddef>
#include <cstdint>

// ---------- types ----------
typedef __attribute__((ext_vector_type(8))) _Float16 half8;
typedef __attribute__((ext_vector_type(4))) _Float16 half4;
typedef __attribute__((ext_vector_type(4))) float f32x4;
typedef __attribute__((ext_vector_type(16))) float f32x16;

#define N_EMBD 1024
#define N_HEADS 16
#define BATCH 4
#define SEQ 2048
#define C3 3072
#define HD 64

__device__ inline uint32_t pk2(float x, float y) {
    auto h2 = __builtin_amdgcn_cvt_pkrtz(x, y);
    uint32_t u;
    __builtin_memcpy(&u, &h2, 4);
    return u;
}

__device__ inline void swap32(uint32_t& a, uint32_t& b) {
    asm volatile("v_permlane32_swap_b32 %0, %1" : "+v"(a), "+v"(b));
}

__device__ inline float exp2_hw(float x) {
    float r;
    asm("v_exp_f32 %0, %1" : "=v"(r) : "v"(x));
    return r;
}

// ---------- fused prep: cvt x (f32->f16) + transpose Wa + transpose Wp ----------
// grid flat 1D, 256 threads. [0, 8192): cvt 32 elems/thread block of x.
// [8192, 8192+3072): Wa transpose tile; [..., +1024): Wp transpose tile.
__device__ inline void transpose_tile(const float* __restrict__ in, _Float16* __restrict__ out,
                                      int R, int Ncols, int bx, int by, int tx, int ty) {
    __shared__ float tile[32][33];
    int n0 = bx * 32, r0 = by * 32;
#pragma unroll
    for (int i = 0; i < 32; i += 8)
        tile[ty + i][tx] = in[(size_t)(r0 + ty + i) * Ncols + n0 + tx];
    __syncthreads();
#pragma unroll
    for (int i = 0; i < 32; i += 8)
        out[(size_t)(n0 + ty + i) * R + r0 + tx] = (_Float16)tile[tx][ty + i];
}

__global__ void prep_kernel(const float* __restrict__ x, _Float16* __restrict__ xh,
                            const float* __restrict__ Wa, _Float16* __restrict__ WaT,
                            const float* __restrict__ Wp, _Float16* __restrict__ WpT) {
    const int bid = blockIdx.x;
    const int tx = threadIdx.x & 31, ty = threadIdx.x >> 5;
    if (bid < 8192) {
        int i = (bid * 256 + threadIdx.x) * 4;
        float4 v = *(const float4*)(x + i);
        half4 h;
        h[0] = (_Float16)v.x; h[1] = (_Float16)v.y; h[2] = (_Float16)v.z; h[3] = (_Float16)v.w;
        *(half4*)(xh + i) = h;
    } else if (bid < 8192 + 3072) {
        int v = bid - 8192;                 // Wa: [1024][3072] -> WaT [3072][1024]
        transpose_tile(Wa, WaT, N_EMBD, C3, v % 96, v / 96, tx, ty);
    } else {
        int v = bid - 8192 - 3072;          // Wp: [1024][1024] -> WpT [1024][1024]
        transpose_tile(Wp, WpT, N_EMBD, N_EMBD, v % 32, v / 32, tx, ty);
    }
}

// ---------- V transpose: qkv V-part [T][64] -> vT[bh][64][T] (f16) ----------
__global__ void transpose_v(const _Float16* __restrict__ qkv, _Float16* __restrict__ vT) {
    __shared__ _Float16 tile[32][36];
    int t0 = blockIdx.x * 32;
    int bhd = blockIdx.y;           // bh*2 + dh
    int bh = bhd >> 1, dh = bhd & 1;
    int b = bh >> 4, h = bh & 15;
    int tx = threadIdx.x, ty = threadIdx.y;  // 32 x 8
#pragma unroll
    for (int i = 0; i < 32; i += 8)
        tile[ty + i][tx] = qkv[(size_t)(b * SEQ + t0 + ty + i) * C3 + 2 * N_EMBD + h * HD + dh * 32 + tx];
    __syncthreads();
#pragma unroll
    for (int i = 0; i < 32; i += 8)
        vT[((size_t)bh * HD + dh * 32 + ty + i) * SEQ + t0 + tx] = tile[tx][ty + i];
}

__device__ inline void store1(float* p, float v) { *p = v; }
__device__ inline void store1(_Float16* p, float v) { *p = (_Float16)v; }

// ---------- 256x192 4-phase GEMM (GEMM1): grid 512 = exactly 2 rounds ----------
template <typename OutT>
__global__ __launch_bounds__(512, 1) void gemm192(
    const _Float16* __restrict__ A, const _Float16* __restrict__ Bt,
    OutT* __restrict__ C, int M, int N, int K) {
    __shared__ _Float16 Al[2][256 * 64];
    __shared__ _Float16 Bl[2][192 * 64];
    const int tid = threadIdx.x;
    const int lane = tid & 63, wave = tid >> 6;
    const int l15 = lane & 15, l4 = lane >> 4;
    const int wm = wave >> 2, wn = wave & 3;

    const int nwg = gridDim.x, nbx = N / 192;
    int wg = blockIdx.x;
    if ((nwg & 7) == 0) { int cpx = nwg >> 3; wg = (wg & 7) * cpx + (wg >> 3); }
    const int row0 = (wg / nbx) * 256, col0 = (wg % nbx) * 192;
    const int TAU = K >> 6;

    const int srow = tid >> 3, su = tid & 7;
    const int usrc8 = (su ^ (srow & 7)) * 8;
    auto stageAu = [&](int unit, int ts) {
        __builtin_amdgcn_global_load_lds(
            (const __attribute__((address_space(1))) void*)(A + (size_t)(row0 + unit * 64 + srow) * K + ts * 64 + usrc8),
            (__attribute__((address_space(3))) void*)(&Al[ts & 1][unit * 64 * 64 + tid * 8]), 16, 0, 0);
    };
    auto stageBu = [&](int unit, int ts) {
        __builtin_amdgcn_global_load_lds(
            (const __attribute__((address_space(1))) void*)(Bt + (size_t)(col0 + unit * 64 + srow) * K + ts * 64 + usrc8),
            (__attribute__((address_space(3))) void*)(&Bl[ts & 1][unit * 64 * 64 + tid * 8]), 16, 0, 0);
    };
    auto stageTile = [&](int ts) {
        stageAu(0, ts); stageAu(1, ts); stageAu(2, ts); stageAu(3, ts);
        stageBu(0, ts); stageBu(1, ts); stageBu(2, ts);
    };

    f32x4 acc[8][3] = {};
    stageTile(0); stageTile(1);
    asm volatile("s_waitcnt vmcnt(7)" ::: "memory");
    __builtin_amdgcn_s_barrier();

    half8 a[4][2], b[3][2];
    for (int tau = 0; tau < TAU; ++tau) {
        const _Float16* Ab = &Al[tau & 1][0];
        const _Float16* Bb = &Bl[tau & 1][0];
        const bool t2 = (tau + 2 < TAU);

        // ---- p0: ds a-half0 + all b ; bar ; MFMA h0 x {n0,n1} ----
#pragma unroll
        for (int m = 0; m < 4; ++m)
#pragma unroll
            for (int ks = 0; ks < 2; ++ks) {
                int r = wm * 128 + m * 16 + l15;
                a[m][ks] = *(const half8*)(Ab + r * 64 + (((ks * 4 + l4) ^ (r & 7)) * 8));
            }
#pragma unroll
        for (int n = 0; n < 3; ++n)
#pragma unroll
            for (int ks = 0; ks < 2; ++ks) {
                int r = wn * 48 + n * 16 + l15;
                b[n][ks] = *(const half8*)(Bb + r * 64 + (((ks * 4 + l4) ^ (r & 7)) * 8));
            }
        __builtin_amdgcn_s_barrier();
        __builtin_amdgcn_s_setprio(1);
#pragma unroll
        for (int m = 0; m < 4; ++m)
#pragma unroll
            for (int n = 0; n < 2; ++n)
#pragma unroll
                for (int ks = 0; ks < 2; ++ks)
                    acc[m][n] = __builtin_amdgcn_mfma_f32_16x16x32_f16(a[m][ks], b[n][ks], acc[m][n], 0, 0, 0);
        __builtin_amdgcn_s_setprio(0);
        __builtin_amdgcn_s_barrier();

        // ---- p1: stage B units (tau+2) ; bar ; MFMA h0 x n2 ----
        if (t2) { stageBu(0, tau + 2); stageBu(1, tau + 2); stageBu(2, tau + 2); }
        __builtin_amdgcn_s_barrier();
        __builtin_amdgcn_s_setprio(1);
#pragma unroll
        for (int m = 0; m < 4; ++m)
#pragma unroll
            for (int ks = 0; ks < 2; ++ks)
                acc[m][2] = __builtin_amdgcn_mfma_f32_16x16x32_f16(a[m][ks], b[2][ks], acc[m][2], 0, 0, 0);
        __builtin_amdgcn_s_setprio(0);
        __builtin_amdgcn_s_barrier();

        // ---- p2: ds a-half1 ; stage A units 0,2 ; bar ; MFMA h1 x {n0,n1} ----
#pragma unroll
        for (int m = 0; m < 4; ++m)
#pragma unroll
            for (int ks = 0; ks < 2; ++ks) {
                int r = wm * 128 + 64 + m * 16 + l15;
                a[m][ks] = *(const half8*)(Ab + r * 64 + (((ks * 4 + l4) ^ (r & 7)) * 8));
            }
        if (t2) { stageAu(0, tau + 2); stageAu(2, tau + 2); }
        __builtin_amdgcn_s_barrier();
        __builtin_amdgcn_s_setprio(1);
#pragma unroll
        for (int m = 0; m < 4; ++m)
#pragma unroll
            for (int n = 0; n < 2; ++n)
#pragma unroll
                for (int ks = 0; ks < 2; ++ks)
                    acc[4 + m][n] = __builtin_amdgcn_mfma_f32_16x16x32_f16(a[m][ks], b[n][ks], acc[4 + m][n], 0, 0, 0);
        __builtin_amdgcn_s_setprio(0);
        __builtin_amdgcn_s_barrier();

        // ---- p3: stage A units 1,3 ; bar ; MFMA h1 x n2 ; vmcnt ; bar ----
        if (t2) { stageAu(1, tau + 2); stageAu(3, tau + 2); }
        __builtin_amdgcn_s_barrier();
        __builtin_amdgcn_s_setprio(1);
#pragma unroll
        for (int m = 0; m < 4; ++m)
#pragma unroll
            for (int ks = 0; ks < 2; ++ks)
                acc[4 + m][2] = __builtin_amdgcn_mfma_f32_16x16x32_f16(a[m][ks], b[2][ks], acc[4 + m][2], 0, 0, 0);
        __builtin_amdgcn_s_setprio(0);
        if (tau <= TAU - 3) {
            asm volatile("s_waitcnt vmcnt(7)" ::: "memory");
        } else if (tau == TAU - 2) {
            asm volatile("s_waitcnt vmcnt(0)" ::: "memory");
        }
        __builtin_amdgcn_s_barrier();
    }

#pragma unroll
    for (int mi = 0; mi < 8; ++mi)
#pragma unroll
        for (int ni = 0; ni < 3; ++ni)
#pragma unroll
            for (int j = 0; j < 4; ++j) {
                int r = row0 + wm * 128 + (mi >> 2) * 64 + (mi & 3) * 16 + l4 * 4 + j;
                int c = col0 + wn * 48 + ni * 16 + l15;
                store1(C + (size_t)r * N + c, acc[mi][ni][j]);
            }
}

// ---------- 128^2 GEMM (GEMM2): 3-buffer ring, counted vmcnt (R6 version) ----------
template <typename OutT>
__global__ __launch_bounds__(256, 2) void gemm_h(
    const _Float16* __restrict__ A, const _Float16* __restrict__ Bt,
    OutT* __restrict__ C, int M, int N, int K) {
    __shared__ _Float16 Al[3][128 * 32];
    __shared__ _Float16 Bl[3][128 * 32];
    const int tid = threadIdx.x;
    const int wave = tid >> 6, lane = tid & 63;
    const int l15 = lane & 15, l4 = lane >> 4;
    const int gx = gridDim.x;
    int lin = blockIdx.y * gx + blockIdx.x;
    int bcol, brow;
    if ((gx & 7) == 0) {
        int cpx = gx >> 3;
        int xcd = lin & 7;
        int idx = lin >> 3;
        bcol = xcd * cpx + idx % cpx;
        brow = idx / cpx;
    } else { bcol = blockIdx.x; brow = blockIdx.y; }
    const int row0 = brow * 128, col0 = bcol * 128;
    const int wm = wave >> 1, wn = wave & 1;
    const int TAU = K >> 5;

    auto stageT = [&](int ts, int buf) {
#pragma unroll
        for (int i = 0; i < 2; ++i) {
            int c = tid + 256 * i;
            int r = c >> 2, c8 = (c & 3) * 8;
            __builtin_amdgcn_global_load_lds(
                (const __attribute__((address_space(1))) void*)(A + (size_t)(row0 + r) * K + ts * 32 + c8),
                (__attribute__((address_space(3))) void*)(&Al[buf][(size_t)(wave * 64 + 256 * i) * 8]),
                16, 0, 0);
        }
#pragma unroll
        for (int i = 0; i < 2; ++i) {
            int c = tid + 256 * i;
            int r = c >> 2, c8 = (c & 3) * 8;
            __builtin_amdgcn_global_load_lds(
                (const __attribute__((address_space(1))) void*)(Bt + (size_t)(col0 + r) * K + ts * 32 + c8),
                (__attribute__((address_space(3))) void*)(&Bl[buf][(size_t)(wave * 64 + 256 * i) * 8]),
                16, 0, 0);
        }
    };

    f32x4 acc[4][4] = {};
    stageT(0, 0); stageT(1, 1);
    asm volatile("s_waitcnt vmcnt(4)" ::: "memory");  // tile 0 landed, tile 1 in flight
    __builtin_amdgcn_s_barrier();

    int cur = 0;
    for (int t = 0; t < TAU; ++t) {
        int sb = cur + 2; if (sb >= 3) sb -= 3;
        if (t + 2 < TAU) stageT(t + 2, sb);
        half8 a[4], b[4];
#pragma unroll
        for (int m = 0; m < 4; ++m)
            a[m] = *(const half8*)(&Al[cur][(wm * 64 + m * 16 + l15) * 32 + l4 * 8]);
#pragma unroll
        for (int n = 0; n < 4; ++n)
            b[n] = *(const half8*)(&Bl[cur][(wn * 64 + n * 16 + l15) * 32 + l4 * 8]);
        __builtin_amdgcn_s_setprio(1);
#pragma unroll
        for (int m = 0; m < 4; ++m)
#pragma unroll
            for (int n = 0; n < 4; ++n)
                acc[m][n] = __builtin_amdgcn_mfma_f32_16x16x32_f16(a[m], b[n], acc[m][n], 0, 0, 0);
        __builtin_amdgcn_s_setprio(0);
        if (t + 2 < TAU) {
            asm volatile("s_waitcnt vmcnt(4)" ::: "memory");  // t+1 landed
        } else if (t + 1 < TAU) {
            asm volatile("s_waitcnt vmcnt(0)" ::: "memory");
        }
        __builtin_amdgcn_s_barrier();
        ++cur; if (cur == 3) cur = 0;
    }
#pragma unroll
    for (int m = 0; m < 4; ++m)
#pragma unroll
        for (int n = 0; n < 4; ++n)
#pragma unroll
            for (int j = 0; j < 4; ++j) {
                int r = row0 + wm * 64 + m * 16 + l4 * 4 + j;
                int cc = col0 + wn * 64 + n * 16 + l15;
                store1(C + (size_t)r * N + cc, acc[m][n][j]);
            }
}

// ---------- flash attention v9: sequential two-pass uniform blocks (R10, kept) ----------
__global__ __launch_bounds__(256, 3) void attn_kernel(const _Float16* __restrict__ qkv,
                                                      const _Float16* __restrict__ vT,
                                                      _Float16* __restrict__ ao) {
    const int bid = blockIdx.x;
    const int pairp = bid >> 6;          // 0..7
    const int bh = bid & 63;
    const int b = bh >> 4, h = bh & 15;
    const int tid = threadIdx.x, lane = tid & 63;
    const int wave = tid >> 6;
    const int l31 = lane & 31, L = lane >> 5;

    __shared__ _Float16 Kl[3][64 * 64];
    __shared__ _Float16 Vl[3][64 * 64];

    const float qscale = 0.125f * 1.44269504089f;
    const float NEGC = -4.0f * 1.44269504089f;

    auto stage = [&](int t, int buf) {
#pragma unroll
        for (int i = 0; i < 2; ++i) {
            int idx = tid + 256 * i;
            int key = idx >> 3;
            int d8 = ((idx & 7) ^ (key & 7)) * 8;
            __builtin_amdgcn_global_load_lds(
                (const __attribute__((address_space(1))) void*)(qkv + (size_t)(b * SEQ + t * 64 + key) * C3 + N_EMBD + h * HD + d8),
                (__attribute__((address_space(3))) void*)(&Kl[buf][idx * 8]), 16, 0, 0);
        }
#pragma unroll
        for (int i = 0; i < 2; ++i) {
            int idx = tid + 256 * i;
            int d = idx >> 3;
            int k8 = ((idx & 7) ^ (d & 7)) * 8;
            __builtin_amdgcn_global_load_lds(
                (const __attribute__((address_space(1))) void*)(vT + ((size_t)bh * HD + d) * SEQ + t * 64 + k8),
                (__attribute__((address_space(3))) void*)(&Vl[buf][idx * 8]), 16, 0, 0);
        }
    };

    half8 onesf;
#pragma unroll
    for (int e = 0; e < 8; ++e) onesf[e] = (_Float16)1.0f;
    const f32x16 cinit = (f32x16)(NEGC);

    for (int pass = 0; pass < 2; ++pass) {
        const int qt = pass ? (15 - pairp) : pairp;
        const int q0w = qt * 128 + wave * 32;
        const int q_g = q0w + l31;
        const int nt = 2 * qt + 2;

        stage(0, 0);
        stage(1, 1);

        half8 qb[4];
#pragma unroll
        for (int ks = 0; ks < 4; ++ks) {
            half8 v = *(const half8*)(qkv + (size_t)(b * SEQ + q_g) * C3 + h * HD + ks * 16 + L * 8);
#pragma unroll
            for (int e = 0; e < 8; ++e) v[e] = (_Float16)((float)v[e] * qscale);
            qb[ks] = v;
        }

        f32x16 o[2];
        o[0] = (f32x16)(0.f);
        o[1] = (f32x16)(0.f);
        f32x16 lac = (f32x16)(0.f);

        asm volatile("s_waitcnt vmcnt(4)" ::: "memory");
        __builtin_amdgcn_s_barrier();

        int cur = 0;
        for (int t = 0; t < nt; ++t) {
            const int kv0 = t * 64;
            int sb = cur + 2; if (sb >= 3) sb -= 3;
            if (t + 2 < nt) stage(t + 2, sb);

            if (kv0 <= q0w + 31) {
                const _Float16* Kb = &Kl[cur][0];
                const _Float16* Vb = &Vl[cur][0];
                f32x16 s[2];
                __builtin_amdgcn_s_setprio(1);
#pragma unroll
                for (int kb = 0; kb < 2; ++kb) {
                    const int key = kb * 32 + l31;
                    {
                        half8 kf = *(const half8*)(Kb + key * 64 + ((L ^ (key & 7)) * 8));
                        s[kb] = __builtin_amdgcn_mfma_f32_32x32x16_f16(kf, qb[0], cinit, 0, 0, 0);
                    }
#pragma unroll
                    for (int ks = 1; ks < 4; ++ks) {
                        half8 kf = *(const half8*)(Kb + key * 64 + (((ks * 2 + L) ^ (key & 7)) * 8));
                        s[kb] = __builtin_amdgcn_mfma_f32_32x32x16_f16(kf, qb[ks], s[kb], 0, 0, 0);
                    }
                }
                __builtin_amdgcn_s_setprio(0);
                const bool needmask = (kv0 + 63 > q0w);
#pragma unroll
                for (int kb = 0; kb < 2; ++kb) {
#pragma unroll
                    for (int r = 0; r < 16; ++r) {
                        float v = exp2_hw(s[kb][r]);
                        if (needmask) {
                            int key_g = kv0 + kb * 32 + (r & 3) + 8 * (r >> 2) + 4 * L;
                            v = (key_g > q_g) ? 0.f : v;
                        }
                        s[kb][r] = v;
                    }
                }
                half8 paf[4];
#pragma unroll
                for (int kb = 0; kb < 2; ++kb)
#pragma unroll
                    for (int hf = 0; hf < 2; ++hf) {
                        const int bse = hf * 8;
                        uint32_t a0 = pk2(s[kb][bse + 0], s[kb][bse + 1]);
                        uint32_t b0 = pk2(s[kb][bse + 4], s[kb][bse + 5]);
                        swap32(a0, b0);
                        uint32_t a1 = pk2(s[kb][bse + 2], s[kb][bse + 3]);
                        uint32_t b1 = pk2(s[kb][bse + 6], s[kb][bse + 7]);
                        swap32(a1, b1);
                        uint32_t w[4] = {a0, a1, b0, b1};
                        __builtin_memcpy(&paf[kb * 2 + hf], w, 16);
                    }
                __builtin_amdgcn_s_setprio(1);
#pragma unroll
                for (int ks = 0; ks < 4; ++ks) {
                    lac = __builtin_amdgcn_mfma_f32_32x32x16_f16(paf[ks], onesf, lac, 0, 0, 0);
#pragma unroll
                    for (int db = 0; db < 2; ++db) {
                        const int d = db * 32 + l31;
                        half8 vb = *(const half8*)(Vb + d * 64 + (((ks * 2 + L) ^ (d & 7)) * 8));
                        o[db] = __builtin_amdgcn_mfma_f32_32x32x16_f16(paf[ks], vb, o[db], 0, 0, 0);
                    }
                }
                __builtin_amdgcn_s_setprio(0);
            }

            if (t + 2 < nt) {
                asm volatile("s_waitcnt vmcnt(4)" ::: "memory");
            } else if (t + 1 < nt) {
                asm volatile("s_waitcnt vmcnt(0)" ::: "memory");
            }
            __builtin_amdgcn_s_barrier();
            ++cur; if (cur == 3) cur = 0;
        }

#pragma unroll
        for (int db = 0; db < 2; ++db)
#pragma unroll
            for (int r = 0; r < 16; ++r) {
                int qg = q0w + (r & 3) + 8 * (r >> 2) + 4 * L;
                ao[(size_t)(b * SEQ + qg) * N_EMBD + h * HD + db * 32 + l31] =
                    (_Float16)(o[db][r] / lac[r]);
            }
    }
}

// ---------- launch ----------
extern "C" void kernel_launch(void* const* d_in, const int* in_sizes, int n_in,
                              void* d_out, int out_size, void* d_ws, size_t ws_size,
                              hipStream_t stream) {
    const float* x  = (const float*)d_in[0];   // [B,T,C]
    const float* Wa = (const float*)d_in[1];   // [C, 3C]
    const float* Wp = (const float*)d_in[2];   // [C, C]
    float* out = (float*)d_out;                // [B,T,C]

    const int M = BATCH * SEQ;                 // 8192
    _Float16* xh  = (_Float16*)d_ws;           // M*C (dead after GEMM1; reused as vT)
    _Float16* WaT = xh + (size_t)M * N_EMBD;                 // [3C][C]
    _Float16* WpT = WaT + (size_t)C3 * N_EMBD;               // [C][C]
    _Float16* qkv = WpT + (size_t)N_EMBD * N_EMBD;           // [M][3C]
    _Float16* ao  = qkv + (size_t)M * C3;                    // [M][C]
    _Float16* vT  = xh;                                      // [64][64][SEQ], aliases xh

    prep_kernel<<<dim3(8192 + 3072 + 1024), 256, 0, stream>>>(x, xh, Wa, WaT, Wp, WpT);

    gemm192<_Float16><<<dim3((M / 256) * (C3 / 192)), 512, 0, stream>>>(xh, WaT, qkv, M, C3, N_EMBD);

    dim3 tb(32, 8);
    transpose_v<<<dim3(SEQ / 32, BATCH * N_HEADS * 2), tb, 0, stream>>>(qkv, vT);

    attn_kernel<<<dim3(512), 256, 0, stream>>>(qkv, vT, ao);

    gemm_h<float><<<dim3(N_EMBD / 128, M / 128), 256, 0, stream>>>(ao, WpT, out, M, N_EMBD, N_EMBD);
}

// Round 12
// 182.209 us; speedup vs baseline: 1.4395x; 1.0145x over previous
//
#include <hip/hip_runtime.h>
#include <cstddef>
#include <cstdint>

// ---------- types ----------
typedef __attribute__((ext_vector_type(8))) _Float16 half8;
typedef __attribute__((ext_vector_type(4))) _Float16 half4;
typedef __attribute__((ext_vector_type(4))) float f32x4;
typedef __attribute__((ext_vector_type(16))) float f32x16;

#define N_EMBD 1024
#define N_HEADS 16
#define BATCH 4
#define SEQ 2048
#define C3 3072
#define HD 64

__device__ inline uint32_t pk2(float x, float y) {
    auto h2 = __builtin_amdgcn_cvt_pkrtz(x, y);
    uint32_t u;
    __builtin_memcpy(&u, &h2, 4);
    return u;
}

__device__ inline void swap32(uint32_t& a, uint32_t& b) {
    asm volatile("v_permlane32_swap_b32 %0, %1" : "+v"(a), "+v"(b));
}

__device__ inline float exp2_hw(float x) {
    float r;
    asm("v_exp_f32 %0, %1" : "=v"(r) : "v"(x));
    return r;
}

// ---------- fused prep: cvt x (f32->f16) + transpose Wa + transpose Wp ----------
__device__ inline void transpose_tile(const float* __restrict__ in, _Float16* __restrict__ out,
                                      int R, int Ncols, int bx, int by, int tx, int ty) {
    __shared__ float tile[32][33];
    int n0 = bx * 32, r0 = by * 32;
#pragma unroll
    for (int i = 0; i < 32; i += 8)
        tile[ty + i][tx] = in[(size_t)(r0 + ty + i) * Ncols + n0 + tx];
    __syncthreads();
#pragma unroll
    for (int i = 0; i < 32; i += 8)
        out[(size_t)(n0 + ty + i) * R + r0 + tx] = (_Float16)tile[tx][ty + i];
}

__global__ void prep_kernel(const float* __restrict__ x, _Float16* __restrict__ xh,
                            const float* __restrict__ Wa, _Float16* __restrict__ WaT,
                            const float* __restrict__ Wp, _Float16* __restrict__ WpT) {
    const int bid = blockIdx.x;
    const int tx = threadIdx.x & 31, ty = threadIdx.x >> 5;
    if (bid < 8192) {
        int i = (bid * 256 + threadIdx.x) * 4;
        float4 v = *(const float4*)(x + i);
        half4 h;
        h[0] = (_Float16)v.x; h[1] = (_Float16)v.y; h[2] = (_Float16)v.z; h[3] = (_Float16)v.w;
        *(half4*)(xh + i) = h;
    } else if (bid < 8192 + 3072) {
        int v = bid - 8192;                 // Wa: [1024][3072] -> WaT [3072][1024]
        transpose_tile(Wa, WaT, N_EMBD, C3, v % 96, v / 96, tx, ty);
    } else {
        int v = bid - 8192 - 3072;          // Wp: [1024][1024] -> WpT [1024][1024]
        transpose_tile(Wp, WpT, N_EMBD, N_EMBD, v % 32, v / 32, tx, ty);
    }
}

// ---------- V transpose: qkv V-part [T][64] -> vT[bh][64][T] (f16) ----------
__global__ void transpose_v(const _Float16* __restrict__ qkv, _Float16* __restrict__ vT) {
    __shared__ _Float16 tile[32][36];
    int t0 = blockIdx.x * 32;
    int bhd = blockIdx.y;           // bh*2 + dh
    int bh = bhd >> 1, dh = bhd & 1;
    int b = bh >> 4, h = bh & 15;
    int tx = threadIdx.x, ty = threadIdx.y;  // 32 x 8
#pragma unroll
    for (int i = 0; i < 32; i += 8)
        tile[ty + i][tx] = qkv[(size_t)(b * SEQ + t0 + ty + i) * C3 + 2 * N_EMBD + h * HD + dh * 32 + tx];
    __syncthreads();
#pragma unroll
    for (int i = 0; i < 32; i += 8)
        vT[((size_t)bh * HD + dh * 32 + ty + i) * SEQ + t0 + tx] = tile[tx][ty + i];
}

__device__ inline void store1(float* p, float v) { *p = v; }
__device__ inline void store1(_Float16* p, float v) { *p = (_Float16)v; }

// ---------- 256x192 4-phase GEMM (GEMM1): grid 512 = exactly 2 rounds ----------
template <typename OutT>
__global__ __launch_bounds__(512, 1) void gemm192(
    const _Float16* __restrict__ A, const _Float16* __restrict__ Bt,
    OutT* __restrict__ C, int M, int N, int K) {
    __shared__ _Float16 Al[2][256 * 64];
    __shared__ _Float16 Bl[2][192 * 64];
    const int tid = threadIdx.x;
    const int lane = tid & 63, wave = tid >> 6;
    const int l15 = lane & 15, l4 = lane >> 4;
    const int wm = wave >> 2, wn = wave & 3;

    const int nwg = gridDim.x, nbx = N / 192;
    int wg = blockIdx.x;
    if ((nwg & 7) == 0) { int cpx = nwg >> 3; wg = (wg & 7) * cpx + (wg >> 3); }
    const int row0 = (wg / nbx) * 256, col0 = (wg % nbx) * 192;
    const int TAU = K >> 6;

    const int srow = tid >> 3, su = tid & 7;
    const int usrc8 = (su ^ (srow & 7)) * 8;
    auto stageAu = [&](int unit, int ts) {
        __builtin_amdgcn_global_load_lds(
            (const __attribute__((address_space(1))) void*)(A + (size_t)(row0 + unit * 64 + srow) * K + ts * 64 + usrc8),
            (__attribute__((address_space(3))) void*)(&Al[ts & 1][unit * 64 * 64 + tid * 8]), 16, 0, 0);
    };
    auto stageBu = [&](int unit, int ts) {
        __builtin_amdgcn_global_load_lds(
            (const __attribute__((address_space(1))) void*)(Bt + (size_t)(col0 + unit * 64 + srow) * K + ts * 64 + usrc8),
            (__attribute__((address_space(3))) void*)(&Bl[ts & 1][unit * 64 * 64 + tid * 8]), 16, 0, 0);
    };
    auto stageTile = [&](int ts) {
        stageAu(0, ts); stageAu(1, ts); stageAu(2, ts); stageAu(3, ts);
        stageBu(0, ts); stageBu(1, ts); stageBu(2, ts);
    };

    f32x4 acc[8][3] = {};
    stageTile(0); stageTile(1);
    asm volatile("s_waitcnt vmcnt(7)" ::: "memory");
    __builtin_amdgcn_s_barrier();

    half8 a[4][2], b[3][2];
    for (int tau = 0; tau < TAU; ++tau) {
        const _Float16* Ab = &Al[tau & 1][0];
        const _Float16* Bb = &Bl[tau & 1][0];
        const bool t2 = (tau + 2 < TAU);

        // ---- p0: ds a-half0 + all b ; bar ; MFMA h0 x {n0,n1} ----
#pragma unroll
        for (int m = 0; m < 4; ++m)
#pragma unroll
            for (int ks = 0; ks < 2; ++ks) {
                int r = wm * 128 + m * 16 + l15;
                a[m][ks] = *(const half8*)(Ab + r * 64 + (((ks * 4 + l4) ^ (r & 7)) * 8));
            }
#pragma unroll
        for (int n = 0; n < 3; ++n)
#pragma unroll
            for (int ks = 0; ks < 2; ++ks) {
                int r = wn * 48 + n * 16 + l15;
                b[n][ks] = *(const half8*)(Bb + r * 64 + (((ks * 4 + l4) ^ (r & 7)) * 8));
            }
        __builtin_amdgcn_s_barrier();
        __builtin_amdgcn_s_setprio(1);
#pragma unroll
        for (int m = 0; m < 4; ++m)
#pragma unroll
            for (int n = 0; n < 2; ++n)
#pragma unroll
                for (int ks = 0; ks < 2; ++ks)
                    acc[m][n] = __builtin_amdgcn_mfma_f32_16x16x32_f16(a[m][ks], b[n][ks], acc[m][n], 0, 0, 0);
        __builtin_amdgcn_s_setprio(0);
        __builtin_amdgcn_s_barrier();

        // ---- p1: stage B units (tau+2) ; bar ; MFMA h0 x n2 ----
        if (t2) { stageBu(0, tau + 2); stageBu(1, tau + 2); stageBu(2, tau + 2); }
        __builtin_amdgcn_s_barrier();
        __builtin_amdgcn_s_setprio(1);
#pragma unroll
        for (int m = 0; m < 4; ++m)
#pragma unroll
            for (int ks = 0; ks < 2; ++ks)
                acc[m][2] = __builtin_amdgcn_mfma_f32_16x16x32_f16(a[m][ks], b[2][ks], acc[m][2], 0, 0, 0);
        __builtin_amdgcn_s_setprio(0);
        __builtin_amdgcn_s_barrier();

        // ---- p2: ds a-half1 ; stage A units 0,2 ; bar ; MFMA h1 x {n0,n1} ----
#pragma unroll
        for (int m = 0; m < 4; ++m)
#pragma unroll
            for (int ks = 0; ks < 2; ++ks) {
                int r = wm * 128 + 64 + m * 16 + l15;
                a[m][ks] = *(const half8*)(Ab + r * 64 + (((ks * 4 + l4) ^ (r & 7)) * 8));
            }
        if (t2) { stageAu(0, tau + 2); stageAu(2, tau + 2); }
        __builtin_amdgcn_s_barrier();
        __builtin_amdgcn_s_setprio(1);
#pragma unroll
        for (int m = 0; m < 4; ++m)
#pragma unroll
            for (int n = 0; n < 2; ++n)
#pragma unroll
                for (int ks = 0; ks < 2; ++ks)
                    acc[4 + m][n] = __builtin_amdgcn_mfma_f32_16x16x32_f16(a[m][ks], b[n][ks], acc[4 + m][n], 0, 0, 0);
        __builtin_amdgcn_s_setprio(0);
        __builtin_amdgcn_s_barrier();

        // ---- p3: stage A units 1,3 ; bar ; MFMA h1 x n2 ; vmcnt ; bar ----
        if (t2) { stageAu(1, tau + 2); stageAu(3, tau + 2); }
        __builtin_amdgcn_s_barrier();
        __builtin_amdgcn_s_setprio(1);
#pragma unroll
        for (int m = 0; m < 4; ++m)
#pragma unroll
            for (int ks = 0; ks < 2; ++ks)
                acc[4 + m][2] = __builtin_amdgcn_mfma_f32_16x16x32_f16(a[m][ks], b[2][ks], acc[4 + m][2], 0, 0, 0);
        __builtin_amdgcn_s_setprio(0);
        if (tau <= TAU - 3) {
            asm volatile("s_waitcnt vmcnt(7)" ::: "memory");
        } else if (tau == TAU - 2) {
            asm volatile("s_waitcnt vmcnt(0)" ::: "memory");
        }
        __builtin_amdgcn_s_barrier();
    }

#pragma unroll
    for (int mi = 0; mi < 8; ++mi)
#pragma unroll
        for (int ni = 0; ni < 3; ++ni)
#pragma unroll
            for (int j = 0; j < 4; ++j) {
                int r = row0 + wm * 128 + (mi >> 2) * 64 + (mi & 3) * 16 + l4 * 4 + j;
                int c = col0 + wn * 48 + ni * 16 + l15;
                store1(C + (size_t)r * N + c, acc[mi][ni][j]);
            }
}

// ---------- 128^2 GEMM (GEMM2): 3-buffer ring, counted vmcnt ----------
template <typename OutT>
__global__ __launch_bounds__(256, 2) void gemm_h(
    const _Float16* __restrict__ A, const _Float16* __restrict__ Bt,
    OutT* __restrict__ C, int M, int N, int K) {
    __shared__ _Float16 Al[3][128 * 32];
    __shared__ _Float16 Bl[3][128 * 32];
    const int tid = threadIdx.x;
    const int wave = tid >> 6, lane = tid & 63;
    const int l15 = lane & 15, l4 = lane >> 4;
    const int gx = gridDim.x;
    int lin = blockIdx.y * gx + blockIdx.x;
    int bcol, brow;
    if ((gx & 7) == 0) {
        int cpx = gx >> 3;
        int xcd = lin & 7;
        int idx = lin >> 3;
        bcol = xcd * cpx + idx % cpx;
        brow = idx / cpx;
    } else { bcol = blockIdx.x; brow = blockIdx.y; }
    const int row0 = brow * 128, col0 = bcol * 128;
    const int wm = wave >> 1, wn = wave & 1;
    const int TAU = K >> 5;

    auto stageT = [&](int ts, int buf) {
#pragma unroll
        for (int i = 0; i < 2; ++i) {
            int c = tid + 256 * i;
            int r = c >> 2, c8 = (c & 3) * 8;
            __builtin_amdgcn_global_load_lds(
                (const __attribute__((address_space(1))) void*)(A + (size_t)(row0 + r) * K + ts * 32 + c8),
                (__attribute__((address_space(3))) void*)(&Al[buf][(size_t)(wave * 64 + 256 * i) * 8]),
                16, 0, 0);
        }
#pragma unroll
        for (int i = 0; i < 2; ++i) {
            int c = tid + 256 * i;
            int r = c >> 2, c8 = (c & 3) * 8;
            __builtin_amdgcn_global_load_lds(
                (const __attribute__((address_space(1))) void*)(Bt + (size_t)(col0 + r) * K + ts * 32 + c8),
                (__attribute__((address_space(3))) void*)(&Bl[buf][(size_t)(wave * 64 + 256 * i) * 8]),
                16, 0, 0);
        }
    };

    f32x4 acc[4][4] = {};
    stageT(0, 0); stageT(1, 1);
    asm volatile("s_waitcnt vmcnt(4)" ::: "memory");
    __builtin_amdgcn_s_barrier();

    int cur = 0;
    for (int t = 0; t < TAU; ++t) {
        int sb = cur + 2; if (sb >= 3) sb -= 3;
        if (t + 2 < TAU) stageT(t + 2, sb);
        half8 a[4], b[4];
#pragma unroll
        for (int m = 0; m < 4; ++m)
            a[m] = *(const half8*)(&Al[cur][(wm * 64 + m * 16 + l15) * 32 + l4 * 8]);
#pragma unroll
        for (int n = 0; n < 4; ++n)
            b[n] = *(const half8*)(&Bl[cur][(wn * 64 + n * 16 + l15) * 32 + l4 * 8]);
        __builtin_amdgcn_s_setprio(1);
#pragma unroll
        for (int m = 0; m < 4; ++m)
#pragma unroll
            for (int n = 0; n < 4; ++n)
                acc[m][n] = __builtin_amdgcn_mfma_f32_16x16x32_f16(a[m], b[n], acc[m][n], 0, 0, 0);
        __builtin_amdgcn_s_setprio(0);
        if (t + 2 < TAU) {
            asm volatile("s_waitcnt vmcnt(4)" ::: "memory");
        } else if (t + 1 < TAU) {
            asm volatile("s_waitcnt vmcnt(0)" ::: "memory");
        }
        __builtin_amdgcn_s_barrier();
        ++cur; if (cur == 3) cur = 0;
    }
#pragma unroll
    for (int m = 0; m < 4; ++m)
#pragma unroll
        for (int n = 0; n < 4; ++n)
#pragma unroll
            for (int j = 0; j < 4; ++j) {
                int r = row0 + wm * 64 + m * 16 + l4 * 4 + j;
                int cc = col0 + wn * 64 + n * 16 + l15;
                store1(C + (size_t)r * N + cc, acc[m][n][j]);
            }
}

// ---------- flash attention v10: v9 + l via VALU partials (ones-MFMA removed) ----------
// Sequential two-pass uniform blocks (R10). PV cluster now 8 MFMAs (was 12);
// l accumulated as chain-broken VALU partials in the exp loop (lane l31 = q),
// redistributed per pass via per-wave l_s LDS bounce (R3-verified pattern).
__global__ __launch_bounds__(256, 3) void attn_kernel(const _Float16* __restrict__ qkv,
                                                      const _Float16* __restrict__ vT,
                                                      _Float16* __restrict__ ao) {
    const int bid = blockIdx.x;
    const int pairp = bid >> 6;          // 0..7
    const int bh = bid & 63;
    const int b = bh >> 4, h = bh & 15;
    const int tid = threadIdx.x, lane = tid & 63;
    const int wave = tid >> 6;
    const int l31 = lane & 31, L = lane >> 5;

    __shared__ _Float16 Kl[3][64 * 64];
    __shared__ _Float16 Vl[3][64 * 64];
    __shared__ float l_s[4][32];

    const float qscale = 0.125f * 1.44269504089f;
    const float NEGC = -4.0f * 1.44269504089f;

    auto stage = [&](int t, int buf) {
#pragma unroll
        for (int i = 0; i < 2; ++i) {
            int idx = tid + 256 * i;
            int key = idx >> 3;
            int d8 = ((idx & 7) ^ (key & 7)) * 8;
            __builtin_amdgcn_global_load_lds(
                (const __attribute__((address_space(1))) void*)(qkv + (size_t)(b * SEQ + t * 64 + key) * C3 + N_EMBD + h * HD + d8),
                (__attribute__((address_space(3))) void*)(&Kl[buf][idx * 8]), 16, 0, 0);
        }
#pragma unroll
        for (int i = 0; i < 2; ++i) {
            int idx = tid + 256 * i;
            int d = idx >> 3;
            int k8 = ((idx & 7) ^ (d & 7)) * 8;
            __builtin_amdgcn_global_load_lds(
                (const __attribute__((address_space(1))) void*)(vT + ((size_t)bh * HD + d) * SEQ + t * 64 + k8),
                (__attribute__((address_space(3))) void*)(&Vl[buf][idx * 8]), 16, 0, 0);
        }
    };

    const f32x16 cinit = (f32x16)(NEGC);

    for (int pass = 0; pass < 2; ++pass) {
        const int qt = pass ? (15 - pairp) : pairp;
        const int q0w = qt * 128 + wave * 32;
        const int q_g = q0w + l31;
        const int nt = 2 * qt + 2;

        stage(0, 0);
        stage(1, 1);

        half8 qb[4];
#pragma unroll
        for (int ks = 0; ks < 4; ++ks) {
            half8 v = *(const half8*)(qkv + (size_t)(b * SEQ + q_g) * C3 + h * HD + ks * 16 + L * 8);
#pragma unroll
            for (int e = 0; e < 8; ++e) v[e] = (_Float16)((float)v[e] * qscale);
            qb[ks] = v;
        }

        f32x16 o[2];
        o[0] = (f32x16)(0.f);
        o[1] = (f32x16)(0.f);
        float ls0 = 0.f, ls1 = 0.f, ls2 = 0.f, ls3 = 0.f;  // chain-broken l partials

        asm volatile("s_waitcnt vmcnt(4)" ::: "memory");
        __builtin_amdgcn_s_barrier();

        int cur = 0;
        for (int t = 0; t < nt; ++t) {
            const int kv0 = t * 64;
            int sb = cur + 2; if (sb >= 3) sb -= 3;
            if (t + 2 < nt) stage(t + 2, sb);

            if (kv0 <= q0w + 31) {
                const _Float16* Kb = &Kl[cur][0];
                const _Float16* Vb = &Vl[cur][0];
                f32x16 s[2];
                __builtin_amdgcn_s_setprio(1);
#pragma unroll
                for (int kb = 0; kb < 2; ++kb) {
                    const int key = kb * 32 + l31;
                    {
                        half8 kf = *(const half8*)(Kb + key * 64 + ((L ^ (key & 7)) * 8));
                        s[kb] = __builtin_amdgcn_mfma_f32_32x32x16_f16(kf, qb[0], cinit, 0, 0, 0);
                    }
#pragma unroll
                    for (int ks = 1; ks < 4; ++ks) {
                        half8 kf = *(const half8*)(Kb + key * 64 + (((ks * 2 + L) ^ (key & 7)) * 8));
                        s[kb] = __builtin_amdgcn_mfma_f32_32x32x16_f16(kf, qb[ks], s[kb], 0, 0, 0);
                    }
                }
                __builtin_amdgcn_s_setprio(0);
                const bool needmask = (kv0 + 63 > q0w);
#pragma unroll
                for (int kb = 0; kb < 2; ++kb) {
#pragma unroll
                    for (int r = 0; r < 16; ++r) {
                        float v = exp2_hw(s[kb][r]);
                        if (needmask) {
                            int key_g = kv0 + kb * 32 + (r & 3) + 8 * (r >> 2) + 4 * L;
                            v = (key_g > q_g) ? 0.f : v;
                        }
                        s[kb][r] = v;
                        if ((r & 3) == 0) ls0 += v;
                        else if ((r & 3) == 1) ls1 += v;
                        else if ((r & 3) == 2) ls2 += v;
                        else ls3 += v;
                    }
                }
                half8 paf[4];
#pragma unroll
                for (int kb = 0; kb < 2; ++kb)
#pragma unroll
                    for (int hf = 0; hf < 2; ++hf) {
                        const int bse = hf * 8;
                        uint32_t a0 = pk2(s[kb][bse + 0], s[kb][bse + 1]);
                        uint32_t b0 = pk2(s[kb][bse + 4], s[kb][bse + 5]);
                        swap32(a0, b0);
                        uint32_t a1 = pk2(s[kb][bse + 2], s[kb][bse + 3]);
                        uint32_t b1 = pk2(s[kb][bse + 6], s[kb][bse + 7]);
                        swap32(a1, b1);
                        uint32_t w[4] = {a0, a1, b0, b1};
                        __builtin_memcpy(&paf[kb * 2 + hf], w, 16);
                    }
                __builtin_amdgcn_s_setprio(1);
#pragma unroll
                for (int ks = 0; ks < 4; ++ks) {
#pragma unroll
                    for (int db = 0; db < 2; ++db) {
                        const int d = db * 32 + l31;
                        half8 vb = *(const half8*)(Vb + d * 64 + (((ks * 2 + L) ^ (d & 7)) * 8));
                        o[db] = __builtin_amdgcn_mfma_f32_32x32x16_f16(paf[ks], vb, o[db], 0, 0, 0);
                    }
                }
                __builtin_amdgcn_s_setprio(0);
            }

            if (t + 2 < nt) {
                asm volatile("s_waitcnt vmcnt(4)" ::: "memory");
            } else if (t + 1 < nt) {
                asm volatile("s_waitcnt vmcnt(0)" ::: "memory");
            }
            __builtin_amdgcn_s_barrier();
            ++cur; if (cur == 3) cur = 0;
        }

        // ---- epilogue: merge l partials + lane halves, redistribute via l_s ----
        float lrow = (ls0 + ls1) + (ls2 + ls3);
        lrow += __shfl_xor(lrow, 32, 64);
        l_s[wave][l31] = lrow;               // both halves write identical value
        asm volatile("s_waitcnt lgkmcnt(0)" ::: "memory");
        __builtin_amdgcn_sched_barrier(0);
        float lq[16];
#pragma unroll
        for (int r = 0; r < 16; ++r)
            lq[r] = l_s[wave][(r & 3) + 8 * (r >> 2) + 4 * L];
        asm volatile("s_waitcnt lgkmcnt(0)" ::: "memory");
        __builtin_amdgcn_sched_barrier(0);
#pragma unroll
        for (int db = 0; db < 2; ++db)
#pragma unroll
            for (int r = 0; r < 16; ++r) {
                int qg = q0w + (r & 3) + 8 * (r >> 2) + 4 * L;
                ao[(size_t)(b * SEQ + qg) * N_EMBD + h * HD + db * 32 + l31] =
                    (_Float16)(o[db][r] / lq[r]);
            }
    }
}

// ---------- launch ----------
extern "C" void kernel_launch(void* const* d_in, const int* in_sizes, int n_in,
                              void* d_out, int out_size, void* d_ws, size_t ws_size,
                              hipStream_t stream) {
    const float* x  = (const float*)d_in[0];   // [B,T,C]
    const float* Wa = (const float*)d_in[1];   // [C, 3C]
    const float* Wp = (const float*)d_in[2];   // [C, C]
    float* out = (float*)d_out;                // [B,T,C]

    const int M = BATCH * SEQ;                 // 8192
    _Float16* xh  = (_Float16*)d_ws;           // M*C (dead after GEMM1; reused as vT)
    _Float16* WaT = xh + (size_t)M * N_EMBD;                 // [3C][C]
    _Float16* WpT = WaT + (size_t)C3 * N_EMBD;               // [C][C]
    _Float16* qkv = WpT + (size_t)N_EMBD * N_EMBD;           // [M][3C]
    _Float16* ao  = qkv + (size_t)M * C3;                    // [M][C]
    _Float16* vT  = xh;                                      // [64][64][SEQ], aliases xh

    prep_kernel<<<dim3(8192 + 3072 + 1024), 256, 0, stream>>>(x, xh, Wa, WaT, Wp, WpT);

    gemm192<_Float16><<<dim3((M / 256) * (C3 / 192)), 512, 0, stream>>>(xh, WaT, qkv, M, C3, N_EMBD);

    dim3 tb(32, 8);
    transpose_v<<<dim3(SEQ / 32, BATCH * N_HEADS * 2), tb, 0, stream>>>(qkv, vT);

    attn_kernel<<<dim3(512), 256, 0, stream>>>(qkv, vT, ao);

    gemm_h<float><<<dim3(N_EMBD / 128, M / 128), 256, 0, stream>>>(ao, WpT, out, M, N_EMBD, N_EMBD);
}

// Round 13
// 168.014 us; speedup vs baseline: 1.5611x; 1.0845x over previous
//
#include <hip/hip_runtime.h>
#include <cstddef>
#include <cstdint>

// ---------- types ----------
typedef __attribute__((ext_vector_type(8))) _Float16 half8;
typedef __attribute__((ext_vector_type(4))) _Float16 half4;
typedef __attribute__((ext_vector_type(4))) float f32x4;
typedef __attribute__((ext_vector_type(16))) float f32x16;

#define N_EMBD 1024
#define N_HEADS 16
#define BATCH 4
#define SEQ 2048
#define C3 3072
#define HD 64

__device__ inline uint32_t pk2(float x, float y) {
    auto h2 = __builtin_amdgcn_cvt_pkrtz(x, y);
    uint32_t u;
    __builtin_memcpy(&u, &h2, 4);
    return u;
}

__device__ inline void swap32(uint32_t& a, uint32_t& b) {
    asm volatile("v_permlane32_swap_b32 %0, %1" : "+v"(a), "+v"(b));
}

__device__ inline float exp2_hw(float x) {
    float r;
    asm("v_exp_f32 %0, %1" : "=v"(r) : "v"(x));
    return r;
}

// ---------- fused prep: cvt x + transpose Wa (Q-cols pre-scaled) + transpose Wp ----------
__device__ inline void transpose_tile(const float* __restrict__ in, _Float16* __restrict__ out,
                                      int R, int Ncols, int bx, int by, int tx, int ty,
                                      int scale_below, float scl) {
    __shared__ float tile[32][33];
    int n0 = bx * 32, r0 = by * 32;
#pragma unroll
    for (int i = 0; i < 32; i += 8)
        tile[ty + i][tx] = in[(size_t)(r0 + ty + i) * Ncols + n0 + tx];
    __syncthreads();
#pragma unroll
    for (int i = 0; i < 32; i += 8) {
        int orow = n0 + ty + i;
        float f = tile[tx][ty + i];
        if (orow < scale_below) f *= scl;
        out[(size_t)orow * R + r0 + tx] = (_Float16)f;
    }
}

__global__ void prep_kernel(const float* __restrict__ x, _Float16* __restrict__ xh,
                            const float* __restrict__ Wa, _Float16* __restrict__ WaT,
                            const float* __restrict__ Wp, _Float16* __restrict__ WpT) {
    const int bid = blockIdx.x;
    const int tx = threadIdx.x & 31, ty = threadIdx.x >> 5;
    const float qscale = 0.125f * 1.44269504089f;  // (1/sqrt(64))*log2(e), folded into Q cols
    if (bid < 8192) {
        int i = (bid * 256 + threadIdx.x) * 4;
        float4 v = *(const float4*)(x + i);
        half4 h;
        h[0] = (_Float16)v.x; h[1] = (_Float16)v.y; h[2] = (_Float16)v.z; h[3] = (_Float16)v.w;
        *(half4*)(xh + i) = h;
    } else if (bid < 8192 + 3072) {
        int v = bid - 8192;                 // Wa: [1024][3072] -> WaT [3072][1024]
        transpose_tile(Wa, WaT, N_EMBD, C3, v % 96, v / 96, tx, ty, N_EMBD, qscale);
    } else {
        int v = bid - 8192 - 3072;          // Wp: [1024][1024] -> WpT [1024][1024]
        transpose_tile(Wp, WpT, N_EMBD, N_EMBD, v % 32, v / 32, tx, ty, 0, 1.0f);
    }
}

// ---------- V transpose (FALLBACK path only, when ws too small for fused) ----------
__global__ void transpose_v(const _Float16* __restrict__ qkv, _Float16* __restrict__ vT) {
    __shared__ _Float16 tile[32][36];
    int t0 = blockIdx.x * 32;
    int bhd = blockIdx.y;           // bh*2 + dh
    int bh = bhd >> 1, dh = bhd & 1;
    int b = bh >> 4, h = bh & 15;
    int tx = threadIdx.x, ty = threadIdx.y;  // 32 x 8
#pragma unroll
    for (int i = 0; i < 32; i += 8)
        tile[ty + i][tx] = qkv[(size_t)(b * SEQ + t0 + ty + i) * C3 + 2 * N_EMBD + h * HD + dh * 32 + tx];
    __syncthreads();
#pragma unroll
    for (int i = 0; i < 32; i += 8)
        vT[((size_t)bh * HD + dh * 32 + ty + i) * SEQ + t0 + tx] = tile[tx][ty + i];
}

__device__ inline void store1(float* p, float v) { *p = v; }
__device__ inline void store1(_Float16* p, float v) { *p = (_Float16)v; }

// ---------- 256x192 4-phase GEMM (GEMM1), V-transpose-fused epilogue ----------
// If vT != nullptr: output cols >= 2048 (the V region) are NOT written to C;
// instead the acc tile is bounced through the dead staging LDS ([192][264]
// transposed) and written to vT[bh][d][t] with coalesced 16B chunks.
__global__ __launch_bounds__(512, 1) void gemm192(
    const _Float16* __restrict__ A, const _Float16* __restrict__ Bt,
    _Float16* __restrict__ C, _Float16* __restrict__ vT, int M, int N, int K) {
    __shared__ _Float16 smem[2 * 256 * 64 + 2 * 192 * 64];  // 112 KB
    _Float16* Al0 = smem;                    // [2][256*64]
    _Float16* Bl0 = smem + 2 * 256 * 64;     // [2][192*64]
    const int tid = threadIdx.x;
    const int lane = tid & 63, wave = tid >> 6;
    const int l15 = lane & 15, l4 = lane >> 4;
    const int wm = wave >> 2, wn = wave & 3;

    const int nwg = gridDim.x, nbx = N / 192;
    int wg = blockIdx.x;
    if ((nwg & 7) == 0) { int cpx = nwg >> 3; wg = (wg & 7) * cpx + (wg >> 3); }
    const int row0 = (wg / nbx) * 256, col0 = (wg % nbx) * 192;
    const int TAU = K >> 6;

    const int srow = tid >> 3, su = tid & 7;
    const int usrc8 = (su ^ (srow & 7)) * 8;
    auto stageAu = [&](int unit, int ts) {
        __builtin_amdgcn_global_load_lds(
            (const __attribute__((address_space(1))) void*)(A + (size_t)(row0 + unit * 64 + srow) * K + ts * 64 + usrc8),
            (__attribute__((address_space(3))) void*)(Al0 + (ts & 1) * 16384 + unit * 4096 + tid * 8), 16, 0, 0);
    };
    auto stageBu = [&](int unit, int ts) {
        __builtin_amdgcn_global_load_lds(
            (const __attribute__((address_space(1))) void*)(Bt + (size_t)(col0 + unit * 64 + srow) * K + ts * 64 + usrc8),
            (__attribute__((address_space(3))) void*)(Bl0 + (ts & 1) * 12288 + unit * 4096 + tid * 8), 16, 0, 0);
    };
    auto stageTile = [&](int ts) {
        stageAu(0, ts); stageAu(1, ts); stageAu(2, ts); stageAu(3, ts);
        stageBu(0, ts); stageBu(1, ts); stageBu(2, ts);
    };

    f32x4 acc[8][3] = {};
    stageTile(0); stageTile(1);
    asm volatile("s_waitcnt vmcnt(7)" ::: "memory");
    __builtin_amdgcn_s_barrier();

    half8 a[4][2], b[3][2];
    for (int tau = 0; tau < TAU; ++tau) {
        const _Float16* Ab = Al0 + (tau & 1) * 16384;
        const _Float16* Bb = Bl0 + (tau & 1) * 12288;
        const bool t2 = (tau + 2 < TAU);

        // ---- p0 ----
#pragma unroll
        for (int m = 0; m < 4; ++m)
#pragma unroll
            for (int ks = 0; ks < 2; ++ks) {
                int r = wm * 128 + m * 16 + l15;
                a[m][ks] = *(const half8*)(Ab + r * 64 + (((ks * 4 + l4) ^ (r & 7)) * 8));
            }
#pragma unroll
        for (int n = 0; n < 3; ++n)
#pragma unroll
            for (int ks = 0; ks < 2; ++ks) {
                int r = wn * 48 + n * 16 + l15;
                b[n][ks] = *(const half8*)(Bb + r * 64 + (((ks * 4 + l4) ^ (r & 7)) * 8));
            }
        __builtin_amdgcn_s_barrier();
        __builtin_amdgcn_s_setprio(1);
#pragma unroll
        for (int m = 0; m < 4; ++m)
#pragma unroll
            for (int n = 0; n < 2; ++n)
#pragma unroll
                for (int ks = 0; ks < 2; ++ks)
                    acc[m][n] = __builtin_amdgcn_mfma_f32_16x16x32_f16(a[m][ks], b[n][ks], acc[m][n], 0, 0, 0);
        __builtin_amdgcn_s_setprio(0);
        __builtin_amdgcn_s_barrier();

        // ---- p1 ----
        if (t2) { stageBu(0, tau + 2); stageBu(1, tau + 2); stageBu(2, tau + 2); }
        __builtin_amdgcn_s_barrier();
        __builtin_amdgcn_s_setprio(1);
#pragma unroll
        for (int m = 0; m < 4; ++m)
#pragma unroll
            for (int ks = 0; ks < 2; ++ks)
                acc[m][2] = __builtin_amdgcn_mfma_f32_16x16x32_f16(a[m][ks], b[2][ks], acc[m][2], 0, 0, 0);
        __builtin_amdgcn_s_setprio(0);
        __builtin_amdgcn_s_barrier();

        // ---- p2 ----
#pragma unroll
        for (int m = 0; m < 4; ++m)
#pragma unroll
            for (int ks = 0; ks < 2; ++ks) {
                int r = wm * 128 + 64 + m * 16 + l15;
                a[m][ks] = *(const half8*)(Ab + r * 64 + (((ks * 4 + l4) ^ (r & 7)) * 8));
            }
        if (t2) { stageAu(0, tau + 2); stageAu(2, tau + 2); }
        __builtin_amdgcn_s_barrier();
        __builtin_amdgcn_s_setprio(1);
#pragma unroll
        for (int m = 0; m < 4; ++m)
#pragma unroll
            for (int n = 0; n < 2; ++n)
#pragma unroll
                for (int ks = 0; ks < 2; ++ks)
                    acc[4 + m][n] = __builtin_amdgcn_mfma_f32_16x16x32_f16(a[m][ks], b[n][ks], acc[4 + m][n], 0, 0, 0);
        __builtin_amdgcn_s_setprio(0);
        __builtin_amdgcn_s_barrier();

        // ---- p3 ----
        if (t2) { stageAu(1, tau + 2); stageAu(3, tau + 2); }
        __builtin_amdgcn_s_barrier();
        __builtin_amdgcn_s_setprio(1);
#pragma unroll
        for (int m = 0; m < 4; ++m)
#pragma unroll
            for (int ks = 0; ks < 2; ++ks)
                acc[4 + m][2] = __builtin_amdgcn_mfma_f32_16x16x32_f16(a[m][ks], b[2][ks], acc[4 + m][2], 0, 0, 0);
        __builtin_amdgcn_s_setprio(0);
        if (tau <= TAU - 3) {
            asm volatile("s_waitcnt vmcnt(7)" ::: "memory");
        } else if (tau == TAU - 2) {
            asm volatile("s_waitcnt vmcnt(0)" ::: "memory");
        }
        __builtin_amdgcn_s_barrier();
    }

    // ---- epilogue ----
    const int vlo = 2 * N_EMBD;                       // V region start col
    const bool fuseV = (vT != nullptr) && (col0 + 192 > vlo);
    _Float16* vbuf = smem;                            // [192][264] transposed bounce
#pragma unroll
    for (int mi = 0; mi < 8; ++mi)
#pragma unroll
        for (int ni = 0; ni < 3; ++ni) {
            int c = col0 + wn * 48 + ni * 16 + l15;
            int rb = wm * 128 + (mi >> 2) * 64 + (mi & 3) * 16 + l4 * 4;
            if ((vT != nullptr) && c >= vlo) {
                if (fuseV) {
                    half4 hv;
#pragma unroll
                    for (int j = 0; j < 4; ++j) hv[j] = (_Float16)acc[mi][ni][j];
                    *(half4*)(&vbuf[(c - col0) * 264 + rb]) = hv;
                }
            } else {
#pragma unroll
                for (int j = 0; j < 4; ++j)
                    store1(C + (size_t)(row0 + rb + j) * N + c, acc[mi][ni][j]);
            }
        }
    if (fuseV) {
        __syncthreads();
        const int vc0 = (col0 > vlo) ? col0 : vlo;
        const int W = col0 + 192 - vc0;               // 64 or 192
        const int nch = W * 32;                       // 16B chunks along t
        const int bB = row0 >> 11;                    // batch
        const int t0 = row0 & 2047;
        for (int ch = tid; ch < nch; ch += 512) {
            int crow = ch >> 5, ck = ch & 31;
            int c = vc0 + crow;
            half8 hv = *(const half8*)(&vbuf[(c - col0) * 264 + ck * 8]);
            int hh = (c - vlo) >> 6, dd = (c - vlo) & 63;
            *(half8*)(&vT[((size_t)(bB * 16 + hh) * 64 + dd) * SEQ + t0 + ck * 8]) = hv;
        }
    }
}

// ---------- 128^2 GEMM (GEMM2): 3-buffer ring, counted vmcnt ----------
template <typename OutT>
__global__ __launch_bounds__(256, 2) void gemm_h(
    const _Float16* __restrict__ A, const _Float16* __restrict__ Bt,
    OutT* __restrict__ C, int M, int N, int K) {
    __shared__ _Float16 Al[3][128 * 32];
    __shared__ _Float16 Bl[3][128 * 32];
    const int tid = threadIdx.x;
    const int wave = tid >> 6, lane = tid & 63;
    const int l15 = lane & 15, l4 = lane >> 4;
    const int gx = gridDim.x;
    int lin = blockIdx.y * gx + blockIdx.x;
    int bcol, brow;
    if ((gx & 7) == 0) {
        int cpx = gx >> 3;
        int xcd = lin & 7;
        int idx = lin >> 3;
        bcol = xcd * cpx + idx % cpx;
        brow = idx / cpx;
    } else { bcol = blockIdx.x; brow = blockIdx.y; }
    const int row0 = brow * 128, col0 = bcol * 128;
    const int wm = wave >> 1, wn = wave & 1;
    const int TAU = K >> 5;

    auto stageT = [&](int ts, int buf) {
#pragma unroll
        for (int i = 0; i < 2; ++i) {
            int c = tid + 256 * i;
            int r = c >> 2, c8 = (c & 3) * 8;
            __builtin_amdgcn_global_load_lds(
                (const __attribute__((address_space(1))) void*)(A + (size_t)(row0 + r) * K + ts * 32 + c8),
                (__attribute__((address_space(3))) void*)(&Al[buf][(size_t)(wave * 64 + 256 * i) * 8]),
                16, 0, 0);
        }
#pragma unroll
        for (int i = 0; i < 2; ++i) {
            int c = tid + 256 * i;
            int r = c >> 2, c8 = (c & 3) * 8;
            __builtin_amdgcn_global_load_lds(
                (const __attribute__((address_space(1))) void*)(Bt + (size_t)(col0 + r) * K + ts * 32 + c8),
                (__attribute__((address_space(3))) void*)(&Bl[buf][(size_t)(wave * 64 + 256 * i) * 8]),
                16, 0, 0);
        }
    };

    f32x4 acc[4][4] = {};
    stageT(0, 0); stageT(1, 1);
    asm volatile("s_waitcnt vmcnt(4)" ::: "memory");
    __builtin_amdgcn_s_barrier();

    int cur = 0;
    for (int t = 0; t < TAU; ++t) {
        int sb = cur + 2; if (sb >= 3) sb -= 3;
        if (t + 2 < TAU) stageT(t + 2, sb);
        half8 a[4], b[4];
#pragma unroll
        for (int m = 0; m < 4; ++m)
            a[m] = *(const half8*)(&Al[cur][(wm * 64 + m * 16 + l15) * 32 + l4 * 8]);
#pragma unroll
        for (int n = 0; n < 4; ++n)
            b[n] = *(const half8*)(&Bl[cur][(wn * 64 + n * 16 + l15) * 32 + l4 * 8]);
        __builtin_amdgcn_s_setprio(1);
#pragma unroll
        for (int m = 0; m < 4; ++m)
#pragma unroll
            for (int n = 0; n < 4; ++n)
                acc[m][n] = __builtin_amdgcn_mfma_f32_16x16x32_f16(a[m], b[n], acc[m][n], 0, 0, 0);
        __builtin_amdgcn_s_setprio(0);
        if (t + 2 < TAU) {
            asm volatile("s_waitcnt vmcnt(4)" ::: "memory");
        } else if (t + 1 < TAU) {
            asm volatile("s_waitcnt vmcnt(0)" ::: "memory");
        }
        __builtin_amdgcn_s_barrier();
        ++cur; if (cur == 3) cur = 0;
    }
#pragma unroll
    for (int m = 0; m < 4; ++m)
#pragma unroll
        for (int n = 0; n < 4; ++n)
#pragma unroll
            for (int j = 0; j < 4; ++j) {
                int r = row0 + wm * 64 + m * 16 + l4 * 4 + j;
                int cc = col0 + wn * 64 + n * 16 + l15;
                store1(C + (size_t)r * N + cc, acc[m][n][j]);
            }
}

// ---------- flash attention v10 (R12, kept; qb scale now pre-folded into WaT) ----------
__global__ __launch_bounds__(256, 3) void attn_kernel(const _Float16* __restrict__ qkv,
                                                      const _Float16* __restrict__ vT,
                                                      _Float16* __restrict__ ao) {
    const int bid = blockIdx.x;
    const int pairp = bid >> 6;          // 0..7
    const int bh = bid & 63;
    const int b = bh >> 4, h = bh & 15;
    const int tid = threadIdx.x, lane = tid & 63;
    const int wave = tid >> 6;
    const int l31 = lane & 31, L = lane >> 5;

    __shared__ _Float16 Kl[3][64 * 64];
    __shared__ _Float16 Vl[3][64 * 64];
    __shared__ float l_s[4][32];

    const float NEGC = -4.0f * 1.44269504089f;

    auto stage = [&](int t, int buf) {
#pragma unroll
        for (int i = 0; i < 2; ++i) {
            int idx = tid + 256 * i;
            int key = idx >> 3;
            int d8 = ((idx & 7) ^ (key & 7)) * 8;
            __builtin_amdgcn_global_load_lds(
                (const __attribute__((address_space(1))) void*)(qkv + (size_t)(b * SEQ + t * 64 + key) * C3 + N_EMBD + h * HD + d8),
                (__attribute__((address_space(3))) void*)(&Kl[buf][idx * 8]), 16, 0, 0);
        }
#pragma unroll
        for (int i = 0; i < 2; ++i) {
            int idx = tid + 256 * i;
            int d = idx >> 3;
            int k8 = ((idx & 7) ^ (d & 7)) * 8;
            __builtin_amdgcn_global_load_lds(
                (const __attribute__((address_space(1))) void*)(vT + ((size_t)bh * HD + d) * SEQ + t * 64 + k8),
                (__attribute__((address_space(3))) void*)(&Vl[buf][idx * 8]), 16, 0, 0);
        }
    };

    const f32x16 cinit = (f32x16)(NEGC);

    for (int pass = 0; pass < 2; ++pass) {
        const int qt = pass ? (15 - pairp) : pairp;
        const int q0w = qt * 128 + wave * 32;
        const int q_g = q0w + l31;
        const int nt = 2 * qt + 2;

        stage(0, 0);
        stage(1, 1);

        half8 qb[4];
#pragma unroll
        for (int ks = 0; ks < 4; ++ks)
            qb[ks] = *(const half8*)(qkv + (size_t)(b * SEQ + q_g) * C3 + h * HD + ks * 16 + L * 8);

        f32x16 o[2];
        o[0] = (f32x16)(0.f);
        o[1] = (f32x16)(0.f);
        float ls0 = 0.f, ls1 = 0.f, ls2 = 0.f, ls3 = 0.f;

        asm volatile("s_waitcnt vmcnt(4)" ::: "memory");
        __builtin_amdgcn_s_barrier();

        int cur = 0;
        for (int t = 0; t < nt; ++t) {
            const int kv0 = t * 64;
            int sb = cur + 2; if (sb >= 3) sb -= 3;
            if (t + 2 < nt) stage(t + 2, sb);

            if (kv0 <= q0w + 31) {
                const _Float16* Kb = &Kl[cur][0];
                const _Float16* Vb = &Vl[cur][0];
                f32x16 s[2];
                __builtin_amdgcn_s_setprio(1);
#pragma unroll
                for (int kb = 0; kb < 2; ++kb) {
                    const int key = kb * 32 + l31;
                    {
                        half8 kf = *(const half8*)(Kb + key * 64 + ((L ^ (key & 7)) * 8));
                        s[kb] = __builtin_amdgcn_mfma_f32_32x32x16_f16(kf, qb[0], cinit, 0, 0, 0);
                    }
#pragma unroll
                    for (int ks = 1; ks < 4; ++ks) {
                        half8 kf = *(const half8*)(Kb + key * 64 + (((ks * 2 + L) ^ (key & 7)) * 8));
                        s[kb] = __builtin_amdgcn_mfma_f32_32x32x16_f16(kf, qb[ks], s[kb], 0, 0, 0);
                    }
                }
                __builtin_amdgcn_s_setprio(0);
                const bool needmask = (kv0 + 63 > q0w);
#pragma unroll
                for (int kb = 0; kb < 2; ++kb) {
#pragma unroll
                    for (int r = 0; r < 16; ++r) {
                        float v = exp2_hw(s[kb][r]);
                        if (needmask) {
                            int key_g = kv0 + kb * 32 + (r & 3) + 8 * (r >> 2) + 4 * L;
                            v = (key_g > q_g) ? 0.f : v;
                        }
                        s[kb][r] = v;
                        if ((r & 3) == 0) ls0 += v;
                        else if ((r & 3) == 1) ls1 += v;
                        else if ((r & 3) == 2) ls2 += v;
                        else ls3 += v;
                    }
                }
                half8 paf[4];
#pragma unroll
                for (int kb = 0; kb < 2; ++kb)
#pragma unroll
                    for (int hf = 0; hf < 2; ++hf) {
                        const int bse = hf * 8;
                        uint32_t a0 = pk2(s[kb][bse + 0], s[kb][bse + 1]);
                        uint32_t b0 = pk2(s[kb][bse + 4], s[kb][bse + 5]);
                        swap32(a0, b0);
                        uint32_t a1 = pk2(s[kb][bse + 2], s[kb][bse + 3]);
                        uint32_t b1 = pk2(s[kb][bse + 6], s[kb][bse + 7]);
                        swap32(a1, b1);
                        uint32_t w[4] = {a0, a1, b0, b1};
                        __builtin_memcpy(&paf[kb * 2 + hf], w, 16);
                    }
                __builtin_amdgcn_s_setprio(1);
#pragma unroll
                for (int ks = 0; ks < 4; ++ks) {
#pragma unroll
                    for (int db = 0; db < 2; ++db) {
                        const int d = db * 32 + l31;
                        half8 vb = *(const half8*)(Vb + d * 64 + (((ks * 2 + L) ^ (d & 7)) * 8));
                        o[db] = __builtin_amdgcn_mfma_f32_32x32x16_f16(paf[ks], vb, o[db], 0, 0, 0);
                    }
                }
                __builtin_amdgcn_s_setprio(0);
            }

            if (t + 2 < nt) {
                asm volatile("s_waitcnt vmcnt(4)" ::: "memory");
            } else if (t + 1 < nt) {
                asm volatile("s_waitcnt vmcnt(0)" ::: "memory");
            }
            __builtin_amdgcn_s_barrier();
            ++cur; if (cur == 3) cur = 0;
        }

        // ---- epilogue: merge l partials + lane halves, redistribute via l_s ----
        float lrow = (ls0 + ls1) + (ls2 + ls3);
        lrow += __shfl_xor(lrow, 32, 64);
        l_s[wave][l31] = lrow;
        asm volatile("s_waitcnt lgkmcnt(0)" ::: "memory");
        __builtin_amdgcn_sched_barrier(0);
        float lq[16];
#pragma unroll
        for (int r = 0; r < 16; ++r)
            lq[r] = l_s[wave][(r & 3) + 8 * (r >> 2) + 4 * L];
        asm volatile("s_waitcnt lgkmcnt(0)" ::: "memory");
        __builtin_amdgcn_sched_barrier(0);
#pragma unroll
        for (int db = 0; db < 2; ++db)
#pragma unroll
            for (int r = 0; r < 16; ++r) {
                int qg = q0w + (r & 3) + 8 * (r >> 2) + 4 * L;
                ao[(size_t)(b * SEQ + qg) * N_EMBD + h * HD + db * 32 + l31] =
                    (_Float16)(o[db][r] / lq[r]);
            }
    }
}

// ---------- launch ----------
extern "C" void kernel_launch(void* const* d_in, const int* in_sizes, int n_in,
                              void* d_out, int out_size, void* d_ws, size_t ws_size,
                              hipStream_t stream) {
    const float* x  = (const float*)d_in[0];   // [B,T,C]
    const float* Wa = (const float*)d_in[1];   // [C, 3C]
    const float* Wp = (const float*)d_in[2];   // [C, C]
    float* out = (float*)d_out;                // [B,T,C]

    const int M = BATCH * SEQ;                 // 8192
    _Float16* xh  = (_Float16*)d_ws;                          // M*C
    _Float16* WaT = xh + (size_t)M * N_EMBD;                  // [3C][C]
    _Float16* WpT = WaT + (size_t)C3 * N_EMBD;                // [C][C]
    _Float16* qkv = WpT + (size_t)N_EMBD * N_EMBD;            // [M][3C]
    _Float16* ao  = qkv + (size_t)M * C3;                     // [M][C]
    _Float16* vTn = ao + (size_t)M * N_EMBD;                  // [64][64][SEQ] (fresh)

    const size_t need = ((size_t)M * N_EMBD * 3 + (size_t)C3 * N_EMBD +
                         (size_t)N_EMBD * N_EMBD + (size_t)M * C3) * sizeof(_Float16);
    const bool fused = (ws_size >= need);
    _Float16* vT = fused ? vTn : xh;           // fallback: alias xh (safe: written after GEMM1)

    prep_kernel<<<dim3(8192 + 3072 + 1024), 256, 0, stream>>>(x, xh, Wa, WaT, Wp, WpT);

    gemm192<<<dim3((M / 256) * (C3 / 192)), 512, 0, stream>>>(
        xh, WaT, qkv, fused ? vT : nullptr, M, C3, N_EMBD);

    if (!fused) {
        dim3 tb(32, 8);
        transpose_v<<<dim3(SEQ / 32, BATCH * N_HEADS * 2), tb, 0, stream>>>(qkv, vT);
    }

    attn_kernel<<<dim3(512), 256, 0, stream>>>(qkv, vT, ao);

    gemm_h<float><<<dim3(N_EMBD / 128, M / 128), 256, 0, stream>>>(ao, WpT, out, M, N_EMBD, N_EMBD);
}